// Round 1
// baseline (729.976 us; speedup 1.0000x reference)
//
#include <hip/hip_runtime.h>
#include <math.h>

#define BB 4
#define TT 1024
#define EE 512
#define HH 8
#define DD 64
#define BT (BB * TT)   // 4096

// ---------------------------------------------------------------------------
// Permute Wk columns so that kp' = kv @ Wkp directly yields K'[j,d] = K[j,(D-d)%D]
// column layout: n = d*H + h  ->  source column ((D-d)%D)*H + h
// ---------------------------------------------------------------------------
__global__ __launch_bounds__(256) void permute_wk_k(const float* __restrict__ Wk,
                                                    float* __restrict__ Wkp) {
    int idx = blockIdx.x * 256 + threadIdx.x;   // 512*512 total
    int col = idx & (EE - 1);
    int row = idx >> 9;
    int d = col >> 3, h = col & 7;
    int sc = (((DD - d) & (DD - 1)) << 3) | h;
    Wkp[idx] = Wk[row * EE + sc];
}

// ---------------------------------------------------------------------------
// fp32 GEMM: C = A(Mx512) @ W(512x512). 64x64 tile per 256-thread block, BK=32.
// splitHeads=0: plain row-major store.
// splitHeads=1: store to head-plane layout  C[h][m][d]  with n = d*H + h.
// ---------------------------------------------------------------------------
__global__ __launch_bounds__(256) void gemm_k(const float* __restrict__ A,
                                              const float* __restrict__ W,
                                              float* __restrict__ Cout,
                                              int splitHeads) {
    __shared__ float As[32][68];   // [k][m], padded
    __shared__ float Ws[32][64];   // [k][n]
    const int t  = threadIdx.x;
    const int m0 = blockIdx.x * 64;
    const int n0 = blockIdx.y * 64;
    const int ty = t >> 4, tx = t & 15;
    float acc[4][4] = {};

    for (int k0 = 0; k0 < EE; k0 += 32) {
        __syncthreads();
        {
            int r = t >> 3, c4 = (t & 7) << 2;
            float4 a0 = *(const float4*)&A[(size_t)(m0 + r) * EE + k0 + c4];
            float4 a1 = *(const float4*)&A[(size_t)(m0 + r + 32) * EE + k0 + c4];
            As[c4 + 0][r] = a0.x; As[c4 + 1][r] = a0.y;
            As[c4 + 2][r] = a0.z; As[c4 + 3][r] = a0.w;
            As[c4 + 0][r + 32] = a1.x; As[c4 + 1][r + 32] = a1.y;
            As[c4 + 2][r + 32] = a1.z; As[c4 + 3][r + 32] = a1.w;
            int rw = t >> 4, cw = (t & 15) << 2;
            *(float4*)&Ws[rw][cw]      = *(const float4*)&W[(size_t)(k0 + rw) * EE + n0 + cw];
            *(float4*)&Ws[rw + 16][cw] = *(const float4*)&W[(size_t)(k0 + rw + 16) * EE + n0 + cw];
        }
        __syncthreads();
#pragma unroll
        for (int k = 0; k < 32; ++k) {
            float4 av = *(const float4*)&As[k][ty << 2];
            float4 bv = *(const float4*)&Ws[k][tx << 2];
            float a[4] = {av.x, av.y, av.z, av.w};
            float b[4] = {bv.x, bv.y, bv.z, bv.w};
#pragma unroll
            for (int i = 0; i < 4; ++i)
#pragma unroll
                for (int j = 0; j < 4; ++j)
                    acc[i][j] = fmaf(a[i], b[j], acc[i][j]);
        }
    }

    if (!splitHeads) {
#pragma unroll
        for (int i = 0; i < 4; ++i) {
            float4 v = make_float4(acc[i][0], acc[i][1], acc[i][2], acc[i][3]);
            *(float4*)&Cout[(size_t)(m0 + (ty << 2) + i) * EE + n0 + (tx << 2)] = v;
        }
    } else {
#pragma unroll
        for (int i = 0; i < 4; ++i)
#pragma unroll
            for (int j = 0; j < 4; ++j) {
                int n = n0 + (tx << 2) + j;
                int h = n & 7, d = n >> 3;
                Cout[(size_t)h * (BT * DD) + (size_t)(m0 + (ty << 2) + i) * DD + d] = acc[i][j];
            }
    }
}

// ---------------------------------------------------------------------------
// Flash attention (fp32). One thread owns one query row. Block = 128 threads,
// grid = (T/128, H, B). K/V tiles of 64 rows staged in LDS (broadcast reads).
// logits = 512 * (Q . K'), online softmax, PV accumulate, store merged-head ctx.
// ---------------------------------------------------------------------------
__global__ __launch_bounds__(128) void attn_k(const float* __restrict__ qh,
                                              const float* __restrict__ kh,
                                              const float* __restrict__ vh,
                                              float* __restrict__ ctx) {
    __shared__ float Ks[64][64];
    __shared__ float Vs[64][64];
    const int t  = threadIdx.x;
    const int q0 = blockIdx.x * 128;
    const int h  = blockIdx.y;
    const int b  = blockIdx.z;
    const size_t plane = (size_t)h * (BT * DD) + (size_t)b * (TT * DD);

    float qreg[64];
    {
        const float4* qsrc = (const float4*)(qh + plane + (size_t)(q0 + t) * DD);
#pragma unroll
        for (int i = 0; i < 16; ++i) {
            float4 v = qsrc[i];
            qreg[4 * i + 0] = v.x; qreg[4 * i + 1] = v.y;
            qreg[4 * i + 2] = v.z; qreg[4 * i + 3] = v.w;
        }
    }
    float acc[64];
#pragma unroll
    for (int i = 0; i < 64; ++i) acc[i] = 0.f;
    float mrun = -1e30f, lrun = 0.f;

    for (int jt = 0; jt < TT / 64; ++jt) {
        __syncthreads();
        {
            const float4* ksrc = (const float4*)(kh + plane + (size_t)jt * 64 * DD);
            const float4* vsrc = (const float4*)(vh + plane + (size_t)jt * 64 * DD);
            float4* kd = (float4*)&Ks[0][0];
            float4* vd = (float4*)&Vs[0][0];
#pragma unroll
            for (int i = 0; i < 8; ++i) {
                kd[t + i * 128] = ksrc[t + i * 128];
                vd[t + i * 128] = vsrc[t + i * 128];
            }
        }
        __syncthreads();

        // process the 64 keys in chunks of 16 (keeps s[] statically indexed)
        for (int cb = 0; cb < 64; cb += 16) {
            float sc[16];
            float cmax = -1e30f;
#pragma unroll
            for (int u = 0; u < 16; ++u) {
                const float4* kr = (const float4*)&Ks[cb + u][0];
                float sum = 0.f;
#pragma unroll
                for (int d4 = 0; d4 < 16; ++d4) {
                    float4 kk = kr[d4];
                    sum = fmaf(qreg[4 * d4 + 0], kk.x, sum);
                    sum = fmaf(qreg[4 * d4 + 1], kk.y, sum);
                    sum = fmaf(qreg[4 * d4 + 2], kk.z, sum);
                    sum = fmaf(qreg[4 * d4 + 3], kk.w, sum);
                }
                float sv = sum * 512.0f;
                sc[u] = sv;
                cmax = fmaxf(cmax, sv);
            }
            float Mn = fmaxf(mrun, cmax);
            float corr = __expf(mrun - Mn);
            lrun *= corr;
#pragma unroll
            for (int i = 0; i < 64; ++i) acc[i] *= corr;
#pragma unroll
            for (int u = 0; u < 16; ++u) {
                float p = __expf(sc[u] - Mn);
                lrun += p;
                const float4* vr = (const float4*)&Vs[cb + u][0];
#pragma unroll
                for (int d4 = 0; d4 < 16; ++d4) {
                    float4 vv = vr[d4];
                    acc[4 * d4 + 0] = fmaf(p, vv.x, acc[4 * d4 + 0]);
                    acc[4 * d4 + 1] = fmaf(p, vv.y, acc[4 * d4 + 1]);
                    acc[4 * d4 + 2] = fmaf(p, vv.z, acc[4 * d4 + 2]);
                    acc[4 * d4 + 3] = fmaf(p, vv.w, acc[4 * d4 + 3]);
                }
            }
            mrun = Mn;
        }
    }

    float inv = 1.0f / lrun;
    float* cd = ctx + (size_t)(b * TT + q0 + t) * EE + h * DD;
#pragma unroll
    for (int i = 0; i < 16; ++i) {
        float4 v = make_float4(acc[4 * i + 0] * inv, acc[4 * i + 1] * inv,
                               acc[4 * i + 2] * inv, acc[4 * i + 3] * inv);
        *(float4*)&cd[4 * i] = v;
    }
}

// ---------------------------------------------------------------------------
extern "C" void kernel_launch(void* const* d_in, const int* in_sizes, int n_in,
                              void* d_out, int out_size, void* d_ws, size_t ws_size,
                              hipStream_t stream) {
    const float* q  = (const float*)d_in[0];
    const float* kv = (const float*)d_in[1];
    const float* Wq = (const float*)d_in[2];
    const float* Wk = (const float*)d_in[3];
    const float* Wv = (const float*)d_in[4];
    const float* Wo = (const float*)d_in[5];
    float* out = (float*)d_out;

    float* ws  = (float*)d_ws;
    const size_t PLANE = (size_t)BT * DD * HH;   // 4096*64*8 = 2,097,152 floats
    float* qh  = ws;                 // [H][B*T][64]
    float* khp = ws + PLANE;         // [H][B*T][64]  (already d-permuted via Wkp)
    float* vh  = ws + 2 * PLANE;     // [H][B*T][64]
    float* ctx = ws + 3 * PLANE;     // [B*T][512]  merged heads
    float* wkp = ws + 4 * PLANE;     // [512][512]

    permute_wk_k<<<dim3((EE * EE) / 256), dim3(256), 0, stream>>>(Wk, wkp);

    dim3 ggrid(BT / 64, EE / 64, 1);
    gemm_k<<<ggrid, dim3(256), 0, stream>>>(q,  Wq,  qh,  1);
    gemm_k<<<ggrid, dim3(256), 0, stream>>>(kv, wkp, khp, 1);
    gemm_k<<<ggrid, dim3(256), 0, stream>>>(kv, Wv,  vh,  1);

    attn_k<<<dim3(TT / 128, HH, BB), dim3(128), 0, stream>>>(qh, khp, vh, ctx);

    gemm_k<<<ggrid, dim3(256), 0, stream>>>(ctx, Wo, out, 0);
}

// Round 2
// 191.787 us; speedup vs baseline: 3.8062x; 3.8062x over previous
//
#include <hip/hip_runtime.h>
#include <math.h>

#define BB 4
#define TT 1024
#define EE 512
#define HH 8
#define DD 64
#define BT (BB * TT)   // 4096
#define KT 32          // keys per staged tile

typedef _Float16 f16;
typedef __attribute__((ext_vector_type(8))) _Float16 f16x8;
typedef __attribute__((ext_vector_type(4))) float f32x4;

// ---------------------------------------------------------------------------
// Permute Wk columns so kp' = kv @ Wkp yields K'[j,d] = K[j,(D-d)%D]
// ---------------------------------------------------------------------------
__global__ __launch_bounds__(256) void permute_wk_k(const float* __restrict__ Wk,
                                                    float* __restrict__ Wkp) {
    int idx = blockIdx.x * 256 + threadIdx.x;
    int col = idx & (EE - 1);
    int row = idx >> 9;
    int d = col >> 3, h = col & 7;
    int sc = (((DD - d) & (DD - 1)) << 3) | h;
    Wkp[idx] = Wk[row * EE + sc];
}

// ---------------------------------------------------------------------------
// fp32 GEMM (unchanged from round 1)
// ---------------------------------------------------------------------------
__global__ __launch_bounds__(256) void gemm_k(const float* __restrict__ A,
                                              const float* __restrict__ W,
                                              float* __restrict__ Cout,
                                              int splitHeads) {
    __shared__ float As[32][68];
    __shared__ float Ws[32][64];
    const int t  = threadIdx.x;
    const int m0 = blockIdx.x * 64;
    const int n0 = blockIdx.y * 64;
    const int ty = t >> 4, tx = t & 15;
    float acc[4][4] = {};

    for (int k0 = 0; k0 < EE; k0 += 32) {
        __syncthreads();
        {
            int r = t >> 3, c4 = (t & 7) << 2;
            float4 a0 = *(const float4*)&A[(size_t)(m0 + r) * EE + k0 + c4];
            float4 a1 = *(const float4*)&A[(size_t)(m0 + r + 32) * EE + k0 + c4];
            As[c4 + 0][r] = a0.x; As[c4 + 1][r] = a0.y;
            As[c4 + 2][r] = a0.z; As[c4 + 3][r] = a0.w;
            As[c4 + 0][r + 32] = a1.x; As[c4 + 1][r + 32] = a1.y;
            As[c4 + 2][r + 32] = a1.z; As[c4 + 3][r + 32] = a1.w;
            int rw = t >> 4, cw = (t & 15) << 2;
            *(float4*)&Ws[rw][cw]      = *(const float4*)&W[(size_t)(k0 + rw) * EE + n0 + cw];
            *(float4*)&Ws[rw + 16][cw] = *(const float4*)&W[(size_t)(k0 + rw + 16) * EE + n0 + cw];
        }
        __syncthreads();
#pragma unroll
        for (int k = 0; k < 32; ++k) {
            float4 av = *(const float4*)&As[k][ty << 2];
            float4 bv = *(const float4*)&Ws[k][tx << 2];
            float a[4] = {av.x, av.y, av.z, av.w};
            float b[4] = {bv.x, bv.y, bv.z, bv.w};
#pragma unroll
            for (int i = 0; i < 4; ++i)
#pragma unroll
                for (int j = 0; j < 4; ++j)
                    acc[i][j] = fmaf(a[i], b[j], acc[i][j]);
        }
    }

    if (!splitHeads) {
#pragma unroll
        for (int i = 0; i < 4; ++i) {
            float4 v = make_float4(acc[i][0], acc[i][1], acc[i][2], acc[i][3]);
            *(float4*)&Cout[(size_t)(m0 + (ty << 2) + i) * EE + n0 + (tx << 2)] = v;
        }
    } else {
#pragma unroll
        for (int i = 0; i < 4; ++i)
#pragma unroll
            for (int j = 0; j < 4; ++j) {
                int n = n0 + (tx << 2) + j;
                int h = n & 7, d = n >> 3;
                Cout[(size_t)h * (BT * DD) + (size_t)(m0 + (ty << 2) + i) * DD + d] = acc[i][j];
            }
    }
}

// ---------------------------------------------------------------------------
// MFMA flash attention. Block = 256 thr (4 waves), each wave owns 16 q rows.
// Grid = (T/64, H, B). Split-fp16 QK^T (3 products), fp16 PV.
// Swapped QK (mfma(K, Q)) -> lane-local softmax; P routed via per-wave LDS.
// ---------------------------------------------------------------------------
__global__ __launch_bounds__(256) void attn_mfma_k(const float* __restrict__ qh,
                                                   const float* __restrict__ kh,
                                                   const float* __restrict__ vh,
                                                   float* __restrict__ ctx) {
    __shared__ __align__(16) f16 Khi[KT][64];   // XOR-swizzled 16B blocks per row
    __shared__ __align__(16) f16 Klo[KT][64];
    __shared__ __align__(16) f16 VT[64][40];    // V^T, padded rows (80 B)
    __shared__ __align__(16) f16 Pl[4][16][40]; // per-wave P[q][key], padded

    const int t  = threadIdx.x;
    const int w  = t >> 6;
    const int l  = t & 63;
    const int lg = l >> 4;     // lane group 0..3
    const int lq = l & 15;
    const int q0 = blockIdx.x * 64 + w * 16;
    const int h  = blockIdx.y;
    const int b  = blockIdx.z;
    const size_t plane = (size_t)h * (BT * DD) + (size_t)b * (TT * DD);

    // ---- Q fragments (B-operand), hi/lo split, x512 folded in (exact) ----
    f16x8 Qhi[2], Qlo[2];
    {
        const float* qrow = qh + plane + (size_t)(q0 + lq) * DD;
#pragma unroll
        for (int kf = 0; kf < 2; ++kf) {
            float4 a = *(const float4*)&qrow[kf * 32 + lg * 8];
            float4 c = *(const float4*)&qrow[kf * 32 + lg * 8 + 4];
            float xs[8] = {a.x, a.y, a.z, a.w, c.x, c.y, c.z, c.w};
            f16x8 hi, lo;
#pragma unroll
            for (int e = 0; e < 8; ++e) {
                float xv = xs[e] * 512.0f;
                f16 hh = (f16)xv;
                hi[e] = hh;
                lo[e] = (f16)(xv - (float)hh);
            }
            Qhi[kf] = hi; Qlo[kf] = lo;
        }
    }

    f32x4 Oacc[4];
#pragma unroll
    for (int i = 0; i < 4; ++i) Oacc[i] = f32x4{0.f, 0.f, 0.f, 0.f};
    float m = -1e30f, lsum = 0.f;

    const int key_t = t >> 3;   // staging: key row 0..31
    const int d8    = t & 7;    // staging: 8-elem chunk 0..7

    for (int kt0 = 0; kt0 < TT; kt0 += KT) {
        __syncthreads();
        // ---- stage K (hi/lo, swizzled) and V^T ----
        {
            const float* krow = kh + plane + (size_t)(kt0 + key_t) * DD + d8 * 8;
            const float* vrow = vh + plane + (size_t)(kt0 + key_t) * DD + d8 * 8;
            float4 k0v = *(const float4*)krow;
            float4 k1v = *(const float4*)(krow + 4);
            float4 v0v = *(const float4*)vrow;
            float4 v1v = *(const float4*)(vrow + 4);
            float kk[8] = {k0v.x, k0v.y, k0v.z, k0v.w, k1v.x, k1v.y, k1v.z, k1v.w};
            float vv[8] = {v0v.x, v0v.y, v0v.z, v0v.w, v1v.x, v1v.y, v1v.z, v1v.w};
            f16x8 khi, klo;
#pragma unroll
            for (int e = 0; e < 8; ++e) {
                f16 hh = (f16)kk[e];
                khi[e] = hh;
                klo[e] = (f16)(kk[e] - (float)hh);
            }
            int dsw = d8 ^ (key_t & 7);
            *(f16x8*)&Khi[key_t][dsw * 8] = khi;
            *(f16x8*)&Klo[key_t][dsw * 8] = klo;
#pragma unroll
            for (int e = 0; e < 8; ++e)
                VT[d8 * 8 + e][key_t] = (f16)vv[e];
        }
        __syncthreads();

        // ---- QK^T (swapped): S^T[key][q], split-fp16 3 products ----
        f32x4 Sc[2];
#pragma unroll
        for (int kt = 0; kt < 2; ++kt) {
            f32x4 c = f32x4{0.f, 0.f, 0.f, 0.f};
            int keyr = kt * 16 + lq;
#pragma unroll
            for (int kf = 0; kf < 2; ++kf) {
                int dblk = kf * 4 + lg;
                int sw = dblk ^ (keyr & 7);
                f16x8 ahi = *(const f16x8*)&Khi[keyr][sw * 8];
                f16x8 alo = *(const f16x8*)&Klo[keyr][sw * 8];
                c = __builtin_amdgcn_mfma_f32_16x16x32_f16(ahi, Qhi[kf], c, 0, 0, 0);
                c = __builtin_amdgcn_mfma_f32_16x16x32_f16(ahi, Qlo[kf], c, 0, 0, 0);
                c = __builtin_amdgcn_mfma_f32_16x16x32_f16(alo, Qhi[kf], c, 0, 0, 0);
            }
            Sc[kt] = c;
        }

        // ---- online softmax for q = lq (keys kt*16 + lg*4 + r live here) ----
        float s[8];
#pragma unroll
        for (int kt = 0; kt < 2; ++kt)
#pragma unroll
            for (int r = 0; r < 4; ++r) s[kt * 4 + r] = Sc[kt][r];
        float tm = s[0];
#pragma unroll
        for (int i = 1; i < 8; ++i) tm = fmaxf(tm, s[i]);
        tm = fmaxf(tm, __shfl_xor(tm, 16));
        tm = fmaxf(tm, __shfl_xor(tm, 32));
        float Mn = fmaxf(m, tm);
        float corr = __expf(m - Mn);
        float ps = 0.f;
        f16 ph[8];
#pragma unroll
        for (int i = 0; i < 8; ++i) {
            float p = __expf(s[i] - Mn);
            ps += p;
            ph[i] = (f16)p;
        }
        ps += __shfl_xor(ps, 16);
        ps += __shfl_xor(ps, 32);
        lsum = lsum * corr + ps;
        m = Mn;

        // ---- write P (fp16, packed pairs) to per-wave LDS ----
#pragma unroll
        for (int kt = 0; kt < 2; ++kt)
#pragma unroll
            for (int rp = 0; rp < 4; rp += 2) {
                union { f16 h; unsigned short u; } u0, u1;
                u0.h = ph[kt * 4 + rp]; u1.h = ph[kt * 4 + rp + 1];
                unsigned int pk = ((unsigned int)u1.u << 16) | u0.u;
                *(unsigned int*)&Pl[w][lq][kt * 16 + lg * 4 + rp] = pk;
            }

        // ---- rescale O (row q = lg*4 + r) ----
        float cq[4];
#pragma unroll
        for (int r = 0; r < 4; ++r) cq[r] = __shfl(corr, lg * 4 + r);
#pragma unroll
        for (int dvt = 0; dvt < 4; ++dvt)
#pragma unroll
            for (int r = 0; r < 4; ++r) Oacc[dvt][r] *= cq[r];

        // ---- PV: O += P @ V ----
        f16x8 pa = *(const f16x8*)&Pl[w][lq][lg * 8];
#pragma unroll
        for (int dvt = 0; dvt < 4; ++dvt) {
            f16x8 bv = *(const f16x8*)&VT[dvt * 16 + lq][lg * 8];
            Oacc[dvt] = __builtin_amdgcn_mfma_f32_16x16x32_f16(pa, bv, Oacc[dvt], 0, 0, 0);
        }
    }

    // ---- normalize and store merged-head ctx ----
    float linv = 1.0f / lsum;
    float lq4[4];
#pragma unroll
    for (int r = 0; r < 4; ++r) lq4[r] = __shfl(linv, lg * 4 + r);
#pragma unroll
    for (int r = 0; r < 4; ++r) {
        float* crow = ctx + (size_t)(b * TT + q0 + lg * 4 + r) * EE + h * DD;
#pragma unroll
        for (int dvt = 0; dvt < 4; ++dvt)
            crow[dvt * 16 + lq] = Oacc[dvt][r] * lq4[r];
    }
}

// ---------------------------------------------------------------------------
extern "C" void kernel_launch(void* const* d_in, const int* in_sizes, int n_in,
                              void* d_out, int out_size, void* d_ws, size_t ws_size,
                              hipStream_t stream) {
    const float* q  = (const float*)d_in[0];
    const float* kv = (const float*)d_in[1];
    const float* Wq = (const float*)d_in[2];
    const float* Wk = (const float*)d_in[3];
    const float* Wv = (const float*)d_in[4];
    const float* Wo = (const float*)d_in[5];
    float* out = (float*)d_out;

    float* ws  = (float*)d_ws;
    const size_t PLANE = (size_t)BT * DD * HH;
    float* qh  = ws;                 // [H][B*T][64]
    float* khp = ws + PLANE;         // [H][B*T][64] (d-permuted via Wkp)
    float* vh  = ws + 2 * PLANE;     // [H][B*T][64]
    float* ctx = ws + 3 * PLANE;     // [B*T][512]
    float* wkp = ws + 4 * PLANE;     // [512][512]

    permute_wk_k<<<dim3((EE * EE) / 256), dim3(256), 0, stream>>>(Wk, wkp);

    dim3 ggrid(BT / 64, EE / 64, 1);
    gemm_k<<<ggrid, dim3(256), 0, stream>>>(q,  Wq,  qh,  1);
    gemm_k<<<ggrid, dim3(256), 0, stream>>>(kv, wkp, khp, 1);
    gemm_k<<<ggrid, dim3(256), 0, stream>>>(kv, Wv,  vh,  1);

    attn_mfma_k<<<dim3(TT / 64, HH, BB), dim3(256), 0, stream>>>(qh, khp, vh, ctx);

    gemm_k<<<ggrid, dim3(256), 0, stream>>>(ctx, Wo, out, 0);
}

// Round 3
// 125.806 us; speedup vs baseline: 5.8024x; 1.5245x over previous
//
#include <hip/hip_runtime.h>
#include <math.h>

#define BB 4
#define TT 1024
#define EE 512
#define HH 8
#define DD 64
#define BT (BB * TT)   // 4096

typedef _Float16 f16;
typedef __attribute__((ext_vector_type(8))) _Float16 f16x8;
typedef __attribute__((ext_vector_type(4))) float f32x4;

// ---------------------------------------------------------------------------
// Prep weights: transposed fp16 planes WT[n][k].
//  which=0: Wq * 512, hi+lo   which=1: Wk col-permuted, hi+lo
//  which=2: Wv hi only        which=3: Wo hi only
// ---------------------------------------------------------------------------
__global__ __launch_bounds__(256) void prep_w_k(const float* __restrict__ Wq,
    const float* __restrict__ Wk, const float* __restrict__ Wv,
    const float* __restrict__ Wo,
    f16* __restrict__ wqh, f16* __restrict__ wql,
    f16* __restrict__ wkh, f16* __restrict__ wkl,
    f16* __restrict__ wvh, f16* __restrict__ woh) {
    int idx = blockIdx.x * 256 + threadIdx.x;   // 512*512
    int k = idx & (EE - 1);
    int n = idx >> 9;
    int which = blockIdx.y;
    if (which == 0) {
        float v = Wq[k * EE + n] * 512.0f;      // fold dk*D scale (exact pow2)
        f16 hi = (f16)v;
        wqh[n * EE + k] = hi;
        wql[n * EE + k] = (f16)(v - (float)hi);
    } else if (which == 1) {
        int d = n >> 3, h = n & 7;
        int sn = (((DD - d) & (DD - 1)) << 3) | h;  // K'[.,d] = K[.,(D-d)%D]
        float v = Wk[k * EE + sn];
        f16 hi = (f16)v;
        wkh[n * EE + k] = hi;
        wkl[n * EE + k] = (f16)(v - (float)hi);
    } else if (which == 2) {
        wvh[n * EE + k] = (f16)Wv[k * EE + n];
    } else {
        woh[n * EE + k] = (f16)Wo[k * EE + n];
    }
}

// ---------------------------------------------------------------------------
// MFMA GEMM: C = A(Mx512) @ W(512x512). Block 256 thr (4 waves), tile 128x64,
// BK=32. Wave w owns rows [w*32, w*32+32) x all 64 n.
// ASPLIT: 0 = A is f16 plain; 1 = A fp32 -> hi only; 2 = A fp32 -> hi+lo
// WSPLIT: weights have lo plane (3-product fp32-class result)
// SMODE:  0 = fp32 row-major [M][512]
//         1 = split f16 head planes  hi/lo [h][m][64]
//         2 = f16 V^T planes [h][d][BT]
// ---------------------------------------------------------------------------
template<int ASPLIT, int WSPLIT, int SMODE>
__global__ __launch_bounds__(256) void mm_k(const void* __restrict__ Aptr,
                                            const f16* __restrict__ WThi,
                                            const f16* __restrict__ WTlo,
                                            void* __restrict__ Out0,
                                            f16* __restrict__ Out1) {
    __shared__ __align__(16) f16 As_hi[128][40];   // padded rows: 80B, 2-way max
    __shared__ __align__(16) f16 As_lo[128][40];
    __shared__ __align__(16) f16 Ws_hi[64][40];
    __shared__ __align__(16) f16 Ws_lo[64][40];
    __shared__ __align__(16) f16 Ep[64][136];      // [n][m] transpose buffer

    const int t = threadIdx.x;
    const int w = t >> 6;
    const int l = t & 63;
    const int fr = l & 15, fc = l >> 4;
    const int m0b = blockIdx.x * 128;
    const int n0b = blockIdx.y * 64;

    f32x4 acc[2][4];
#pragma unroll
    for (int i = 0; i < 2; ++i)
#pragma unroll
        for (int j = 0; j < 4; ++j) acc[i][j] = f32x4{0.f, 0.f, 0.f, 0.f};

    for (int k0 = 0; k0 < EE; k0 += 32) {
        __syncthreads();
        if (ASPLIT >= 1) {
            const float* A = (const float*)Aptr;
            int r = t >> 1, hf = t & 1;
            const float* src = A + (size_t)(m0b + r) * EE + k0 + hf * 16;
            float4 a0 = ((const float4*)src)[0];
            float4 a1 = ((const float4*)src)[1];
            float4 a2 = ((const float4*)src)[2];
            float4 a3 = ((const float4*)src)[3];
            float xs[16] = {a0.x, a0.y, a0.z, a0.w, a1.x, a1.y, a1.z, a1.w,
                            a2.x, a2.y, a2.z, a2.w, a3.x, a3.y, a3.z, a3.w};
            f16x8 h0, h1, l0, l1;
#pragma unroll
            for (int e = 0; e < 8; ++e) {
                f16 ha = (f16)xs[e];     h0[e] = ha;
                f16 hb = (f16)xs[8 + e]; h1[e] = hb;
                if (ASPLIT == 2) {
                    l0[e] = (f16)(xs[e] - (float)ha);
                    l1[e] = (f16)(xs[8 + e] - (float)hb);
                }
            }
            *(f16x8*)&As_hi[r][hf * 16]     = h0;
            *(f16x8*)&As_hi[r][hf * 16 + 8] = h1;
            if (ASPLIT == 2) {
                *(f16x8*)&As_lo[r][hf * 16]     = l0;
                *(f16x8*)&As_lo[r][hf * 16 + 8] = l1;
            }
        } else {
            const f16* A = (const f16*)Aptr;
#pragma unroll
            for (int i = 0; i < 2; ++i) {
                int slot = t * 2 + i;
                int r = slot >> 2, ch = slot & 3;
                *(f16x8*)&As_hi[r][ch * 8] =
                    *(const f16x8*)&A[(size_t)(m0b + r) * EE + k0 + ch * 8];
            }
        }
        {
            int r = t >> 2, ch = t & 3;
            *(f16x8*)&Ws_hi[r][ch * 8] =
                *(const f16x8*)&WThi[(size_t)(n0b + r) * EE + k0 + ch * 8];
            if (WSPLIT)
                *(f16x8*)&Ws_lo[r][ch * 8] =
                    *(const f16x8*)&WTlo[(size_t)(n0b + r) * EE + k0 + ch * 8];
        }
        __syncthreads();

        f16x8 Ah[2], Al[2], Bh[4], Bl[4];
#pragma unroll
        for (int mi = 0; mi < 2; ++mi) {
            Ah[mi] = *(const f16x8*)&As_hi[w * 32 + mi * 16 + fr][fc * 8];
            if (ASPLIT == 2)
                Al[mi] = *(const f16x8*)&As_lo[w * 32 + mi * 16 + fr][fc * 8];
        }
#pragma unroll
        for (int nj = 0; nj < 4; ++nj) {
            Bh[nj] = *(const f16x8*)&Ws_hi[nj * 16 + fr][fc * 8];
            if (WSPLIT) Bl[nj] = *(const f16x8*)&Ws_lo[nj * 16 + fr][fc * 8];
        }
#pragma unroll
        for (int mi = 0; mi < 2; ++mi)
#pragma unroll
            for (int nj = 0; nj < 4; ++nj) {
                acc[mi][nj] = __builtin_amdgcn_mfma_f32_16x16x32_f16(
                    Ah[mi], Bh[nj], acc[mi][nj], 0, 0, 0);
                if (WSPLIT)
                    acc[mi][nj] = __builtin_amdgcn_mfma_f32_16x16x32_f16(
                        Ah[mi], Bl[nj], acc[mi][nj], 0, 0, 0);
                if (ASPLIT == 2)
                    acc[mi][nj] = __builtin_amdgcn_mfma_f32_16x16x32_f16(
                        Al[mi], Bh[nj], acc[mi][nj], 0, 0, 0);
            }
    }

    if (SMODE == 0) {
        float* out = (float*)Out0;
#pragma unroll
        for (int mi = 0; mi < 2; ++mi)
#pragma unroll
            for (int nj = 0; nj < 4; ++nj)
#pragma unroll
                for (int r = 0; r < 4; ++r)
                    out[(size_t)(m0b + w * 32 + mi * 16 + fc * 4 + r) * EE +
                        n0b + nj * 16 + fr] = acc[mi][nj][r];
        return;
    }

    // ---- head-layout stores via LDS transpose (coalesced 16B stores) ----
    __syncthreads();
#pragma unroll
    for (int mi = 0; mi < 2; ++mi)
#pragma unroll
        for (int nj = 0; nj < 4; ++nj)
#pragma unroll
            for (int r = 0; r < 4; ++r)
                Ep[nj * 16 + fr][w * 32 + mi * 16 + fc * 4 + r] = (f16)acc[mi][nj][r];
    __syncthreads();
    if (SMODE == 1) {
        f16* dhi = (f16*)Out0;
#pragma unroll
        for (int i = 0; i < 4; ++i) {
            int task = t * 4 + i;               // 1024 tasks: (mr 0..127, h 0..7)
            int mr = task >> 3, h = task & 7;
            f16x8 v;
#pragma unroll
            for (int d = 0; d < 8; ++d) v[d] = Ep[8 * d + h][mr];
            *(f16x8*)&dhi[((size_t)h * BT + m0b + mr) * DD + (n0b >> 3)] = v;
        }
        __syncthreads();
#pragma unroll
        for (int mi = 0; mi < 2; ++mi)
#pragma unroll
            for (int nj = 0; nj < 4; ++nj)
#pragma unroll
                for (int r = 0; r < 4; ++r) {
                    float x = acc[mi][nj][r];
                    f16 hh = (f16)x;
                    Ep[nj * 16 + fr][w * 32 + mi * 16 + fc * 4 + r] =
                        (f16)(x - (float)hh);
                }
        __syncthreads();
#pragma unroll
        for (int i = 0; i < 4; ++i) {
            int task = t * 4 + i;
            int mr = task >> 3, h = task & 7;
            f16x8 v;
#pragma unroll
            for (int d = 0; d < 8; ++d) v[d] = Ep[8 * d + h][mr];
            *(f16x8*)&Out1[((size_t)h * BT + m0b + mr) * DD + (n0b >> 3)] = v;
        }
    } else {   // SMODE == 2: V^T planes [h][d][BT]
        f16* dst = (f16*)Out0;
#pragma unroll
        for (int i = 0; i < 4; ++i) {
            int task = t * 4 + i;               // (n 0..63, mg 0..15)
            int mg = task & 15, n = task >> 4;
            int dloc = n >> 3, h = n & 7;
            f16x8 v = *(const f16x8*)&Ep[n][mg * 8];
            *(f16x8*)&dst[((size_t)(h * DD + (n0b >> 3) + dloc)) * BT +
                          m0b + mg * 8] = v;
        }
    }
}

// ---------------------------------------------------------------------------
// MFMA flash attention, fp16 pre-split inputs, V already transposed.
// Block = 4 waves x 16 q rows. Grid (T/64, H, B).
// ---------------------------------------------------------------------------
__global__ __launch_bounds__(256) void attn_mfma_k(const f16* __restrict__ qhiP,
    const f16* __restrict__ qloP, const f16* __restrict__ khiP,
    const f16* __restrict__ kloP, const f16* __restrict__ vTP,
    f16* __restrict__ ctx) {
    __shared__ __align__(16) f16 Khi[32][64];   // XOR-swizzled 16B chunks
    __shared__ __align__(16) f16 Klo[32][64];
    __shared__ __align__(16) f16 VT[64][40];    // [d][key], padded
    __shared__ __align__(16) f16 Pl[4][16][40]; // per-wave P[q][key]

    const int t  = threadIdx.x;
    const int w  = t >> 6;
    const int l  = t & 63;
    const int lg = l >> 4;
    const int lq = l & 15;
    const int q0 = blockIdx.x * 64 + w * 16;
    const int h  = blockIdx.y;
    const int b  = blockIdx.z;
    const size_t plane = ((size_t)h * BT + (size_t)b * TT) * DD;

    f16x8 Qhi[2], Qlo[2];
#pragma unroll
    for (int kf = 0; kf < 2; ++kf) {
        size_t qo = plane + (size_t)(q0 + lq) * DD + kf * 32 + lg * 8;
        Qhi[kf] = *(const f16x8*)&qhiP[qo];
        Qlo[kf] = *(const f16x8*)&qloP[qo];
    }

    f32x4 Oacc[4];
#pragma unroll
    for (int i = 0; i < 4; ++i) Oacc[i] = f32x4{0.f, 0.f, 0.f, 0.f};
    float m = -1e30f, lsum = 0.f;

    const int key_t = t >> 3, d8 = t & 7;   // K staging roles
    const int vrow = t >> 2, vch = t & 3;   // V staging roles

    for (int kt0 = 0; kt0 < TT; kt0 += 32) {
        __syncthreads();
        {
            size_t off = plane + (size_t)(kt0 + key_t) * DD + d8 * 8;
            f16x8 kh8 = *(const f16x8*)&khiP[off];
            f16x8 kl8 = *(const f16x8*)&kloP[off];
            int dsw = d8 ^ (key_t & 7);
            *(f16x8*)&Khi[key_t][dsw * 8] = kh8;
            *(f16x8*)&Klo[key_t][dsw * 8] = kl8;
            *(f16x8*)&VT[vrow][vch * 8] =
                *(const f16x8*)&vTP[((size_t)h * DD + vrow) * BT +
                                    (size_t)b * TT + kt0 + vch * 8];
        }
        __syncthreads();

        // ---- QK^T (swapped): S^T[key][q], 3-product split fp16 ----
        f32x4 Sc[2];
#pragma unroll
        for (int kt = 0; kt < 2; ++kt) {
            f32x4 c = f32x4{0.f, 0.f, 0.f, 0.f};
            int keyr = kt * 16 + lq;
#pragma unroll
            for (int kf = 0; kf < 2; ++kf) {
                int dblk = kf * 4 + lg;
                int sw = dblk ^ (keyr & 7);
                f16x8 ahi = *(const f16x8*)&Khi[keyr][sw * 8];
                f16x8 alo = *(const f16x8*)&Klo[keyr][sw * 8];
                c = __builtin_amdgcn_mfma_f32_16x16x32_f16(ahi, Qhi[kf], c, 0, 0, 0);
                c = __builtin_amdgcn_mfma_f32_16x16x32_f16(ahi, Qlo[kf], c, 0, 0, 0);
                c = __builtin_amdgcn_mfma_f32_16x16x32_f16(alo, Qhi[kf], c, 0, 0, 0);
            }
            Sc[kt] = c;
        }

        // ---- online softmax for q-row lq ----
        float s[8];
#pragma unroll
        for (int kt = 0; kt < 2; ++kt)
#pragma unroll
            for (int r = 0; r < 4; ++r) s[kt * 4 + r] = Sc[kt][r];
        float tm = s[0];
#pragma unroll
        for (int i = 1; i < 8; ++i) tm = fmaxf(tm, s[i]);
        tm = fmaxf(tm, __shfl_xor(tm, 16));
        tm = fmaxf(tm, __shfl_xor(tm, 32));
        float Mn = fmaxf(m, tm);
        float corr = __expf(m - Mn);
        float ps = 0.f;
        f16 ph[8];
#pragma unroll
        for (int i = 0; i < 8; ++i) {
            float p = __expf(s[i] - Mn);
            ps += p;
            ph[i] = (f16)p;
        }
        ps += __shfl_xor(ps, 16);
        ps += __shfl_xor(ps, 32);
        lsum = lsum * corr + ps;
        m = Mn;

#pragma unroll
        for (int kt = 0; kt < 2; ++kt)
#pragma unroll
            for (int rp = 0; rp < 4; rp += 2) {
                union { f16 h; unsigned short u; } u0, u1;
                u0.h = ph[kt * 4 + rp]; u1.h = ph[kt * 4 + rp + 1];
                unsigned int pk = ((unsigned int)u1.u << 16) | u0.u;
                *(unsigned int*)&Pl[w][lq][kt * 16 + lg * 4 + rp] = pk;
            }

        float cq[4];
#pragma unroll
        for (int r = 0; r < 4; ++r) cq[r] = __shfl(corr, lg * 4 + r);
#pragma unroll
        for (int dvt = 0; dvt < 4; ++dvt)
#pragma unroll
            for (int r = 0; r < 4; ++r) Oacc[dvt][r] *= cq[r];

        f16x8 pa = *(const f16x8*)&Pl[w][lq][lg * 8];
#pragma unroll
        for (int dvt = 0; dvt < 4; ++dvt) {
            f16x8 bv = *(const f16x8*)&VT[dvt * 16 + lq][lg * 8];
            Oacc[dvt] = __builtin_amdgcn_mfma_f32_16x16x32_f16(pa, bv, Oacc[dvt], 0, 0, 0);
        }
    }

    float linv = 1.0f / lsum;
    float lq4[4];
#pragma unroll
    for (int r = 0; r < 4; ++r) lq4[r] = __shfl(linv, lg * 4 + r);
#pragma unroll
    for (int r = 0; r < 4; ++r) {
        f16* crow = ctx + (size_t)(b * TT + q0 + lg * 4 + r) * EE + h * DD;
#pragma unroll
        for (int dvt = 0; dvt < 4; ++dvt)
            crow[dvt * 16 + lq] = (f16)(Oacc[dvt][r] * lq4[r]);
    }
}

// ---------------------------------------------------------------------------
extern "C" void kernel_launch(void* const* d_in, const int* in_sizes, int n_in,
                              void* d_out, int out_size, void* d_ws, size_t ws_size,
                              hipStream_t stream) {
    const float* q  = (const float*)d_in[0];
    const float* kv = (const float*)d_in[1];
    const float* Wq = (const float*)d_in[2];
    const float* Wk = (const float*)d_in[3];
    const float* Wv = (const float*)d_in[4];
    const float* Wo = (const float*)d_in[5];
    float* out = (float*)d_out;

    f16* ws = (f16*)d_ws;
    const size_t PL  = (size_t)HH * BT * DD;   // 2,097,152 f16 per plane
    const size_t WPL = (size_t)EE * EE;        // 262,144 f16 per weight plane
    f16* qhi = ws + 0 * PL;
    f16* qlo = ws + 1 * PL;
    f16* khi = ws + 2 * PL;
    f16* klo = ws + 3 * PL;
    f16* vT  = ws + 4 * PL;      // [H][64][BT]
    f16* ctx = ws + 5 * PL;      // [BT][512]
    f16* wqh = ws + 6 * PL;
    f16* wql = wqh + 1 * WPL;
    f16* wkh = wqh + 2 * WPL;
    f16* wkl = wqh + 3 * WPL;
    f16* wvh = wqh + 4 * WPL;
    f16* woh = wqh + 5 * WPL;

    prep_w_k<<<dim3((EE * EE) / 256, 4), dim3(256), 0, stream>>>(
        Wq, Wk, Wv, Wo, wqh, wql, wkh, wkl, wvh, woh);

    dim3 ggrid(BT / 128, EE / 64);
    mm_k<2, 1, 1><<<ggrid, dim3(256), 0, stream>>>(q,  wqh, wql, qhi, qlo);
    mm_k<2, 1, 1><<<ggrid, dim3(256), 0, stream>>>(kv, wkh, wkl, khi, klo);
    mm_k<1, 0, 2><<<ggrid, dim3(256), 0, stream>>>(kv, wvh, nullptr, vT, nullptr);

    attn_mfma_k<<<dim3(TT / 64, HH, BB), dim3(256), 0, stream>>>(
        qhi, qlo, khi, klo, vT, ctx);

    mm_k<0, 0, 0><<<ggrid, dim3(256), 0, stream>>>(ctx, woh, nullptr, out, nullptr);
}

// Round 4
// 92.393 us; speedup vs baseline: 7.9008x; 1.3616x over previous
//
#include <hip/hip_runtime.h>
#include <math.h>

#define BB 4
#define TT 1024
#define EE 512
#define HH 8
#define DD 64
#define BT (BB * TT)   // 4096

typedef _Float16 f16;
typedef __attribute__((ext_vector_type(8))) _Float16 f16x8;
typedef __attribute__((ext_vector_type(4))) float f32x4;

// ---------------------------------------------------------------------------
// Prep weights: transposed fp16 planes WT[n][k].
//  which=0: Wq * 512, hi+lo   which=1: Wk col-permuted, hi+lo
//  which=2: Wv hi only        which=3: Wo hi only
// ---------------------------------------------------------------------------
__global__ __launch_bounds__(256) void prep_w_k(const float* __restrict__ Wq,
    const float* __restrict__ Wk, const float* __restrict__ Wv,
    const float* __restrict__ Wo,
    f16* __restrict__ wqh, f16* __restrict__ wql,
    f16* __restrict__ wkh, f16* __restrict__ wkl,
    f16* __restrict__ wvh, f16* __restrict__ woh) {
    int idx = blockIdx.x * 256 + threadIdx.x;   // 512*512
    int k = idx & (EE - 1);
    int n = idx >> 9;
    int which = blockIdx.y;
    if (which == 0) {
        float v = Wq[k * EE + n] * 512.0f;      // fold dk*D scale (exact pow2)
        f16 hi = (f16)v;
        wqh[n * EE + k] = hi;
        wql[n * EE + k] = (f16)(v - (float)hi);
    } else if (which == 1) {
        int d = n >> 3, h = n & 7;
        int sn = (((DD - d) & (DD - 1)) << 3) | h;  // K'[.,d] = K[.,(D-d)%D]
        float v = Wk[k * EE + sn];
        f16 hi = (f16)v;
        wkh[n * EE + k] = hi;
        wkl[n * EE + k] = (f16)(v - (float)hi);
    } else if (which == 2) {
        wvh[n * EE + k] = (f16)Wv[k * EE + n];
    } else {
        woh[n * EE + k] = (f16)Wo[k * EE + n];
    }
}

// ---------------------------------------------------------------------------
// MFMA GEMM: C = A(Mx512) @ W(512x512). Block 256 thr (4 waves), tile 64x64,
// BK=32, double-buffered LDS + reg-staged prefetch (1 barrier per k-step).
// Wave (wm,wn) owns 32x32 quadrant. Grid (BT/64, EE/64) = (64,8).
// ASPLIT: 0 = A f16; 1 = A fp32 -> hi only; 2 = A fp32 -> hi+lo
// WSPLIT: weights have lo plane (3-product fp32-class)
// SMODE:  0 = fp32 row-major; 1 = split f16 head planes; 2 = f16 V^T planes
// ---------------------------------------------------------------------------
template<int ASPLIT, int WSPLIT, int SMODE>
__global__ __launch_bounds__(256) void mm_k(const void* __restrict__ Aptr,
                                            const f16* __restrict__ WThi,
                                            const f16* __restrict__ WTlo,
                                            void* __restrict__ Out0,
                                            f16* __restrict__ Out1) {
    __shared__ __align__(16) f16 Ah_s[2][64][40];
    __shared__ __align__(16) f16 Al_s[ASPLIT == 2 ? 2 : 1][ASPLIT == 2 ? 64 : 1][40];
    __shared__ __align__(16) f16 Wh_s[2][64][40];
    __shared__ __align__(16) f16 Wl_s[WSPLIT ? 2 : 1][WSPLIT ? 64 : 1][40];
    __shared__ __align__(16) f16 Ep[SMODE ? 64 : 1][72];

    const int t = threadIdx.x;
    const int w = t >> 6, l = t & 63;
    const int wm = w >> 1, wn = w & 1;
    const int fr = l & 15, fc = l >> 4;
    const int m0b = blockIdx.x * 64;
    const int n0b = blockIdx.y * 64;
    const int sr = t >> 2, sch = t & 3;

    f32x4 acc[2][2];
#pragma unroll
    for (int i = 0; i < 2; ++i)
#pragma unroll
        for (int j = 0; j < 2; ++j) acc[i][j] = f32x4{0.f, 0.f, 0.f, 0.f};

    float4 a4x[2];
    f16x8 af, wh8, wl8;

    auto loadAB = [&](int k0) {
        if (ASPLIT >= 1) {
            const float* A = (const float*)Aptr;
            const float* src = A + (size_t)(m0b + sr) * EE + k0 + sch * 8;
            a4x[0] = ((const float4*)src)[0];
            a4x[1] = ((const float4*)src)[1];
        } else {
            const f16* A = (const f16*)Aptr;
            af = *(const f16x8*)&A[(size_t)(m0b + sr) * EE + k0 + sch * 8];
        }
        wh8 = *(const f16x8*)&WThi[(size_t)(n0b + sr) * EE + k0 + sch * 8];
        if (WSPLIT)
            wl8 = *(const f16x8*)&WTlo[(size_t)(n0b + sr) * EE + k0 + sch * 8];
    };
    auto stage = [&](int bf) {
        if (ASPLIT >= 1) {
            float xs[8] = {a4x[0].x, a4x[0].y, a4x[0].z, a4x[0].w,
                           a4x[1].x, a4x[1].y, a4x[1].z, a4x[1].w};
            f16x8 hi, lo;
#pragma unroll
            for (int e = 0; e < 8; ++e) {
                f16 hh = (f16)xs[e];
                hi[e] = hh;
                if (ASPLIT == 2) lo[e] = (f16)(xs[e] - (float)hh);
            }
            *(f16x8*)&Ah_s[bf][sr][sch * 8] = hi;
            if (ASPLIT == 2) *(f16x8*)&Al_s[bf][sr][sch * 8] = lo;
        } else {
            *(f16x8*)&Ah_s[bf][sr][sch * 8] = af;
        }
        *(f16x8*)&Wh_s[bf][sr][sch * 8] = wh8;
        if (WSPLIT) *(f16x8*)&Wl_s[bf][sr][sch * 8] = wl8;
    };

    loadAB(0);
    stage(0);
    __syncthreads();
    int cur = 0;
    for (int ks = 0; ks < 16; ++ks) {
        if (ks < 15) loadAB((ks + 1) * 32);
        f16x8 Ahf[2], Alf[2], Bhf[2], Blf[2];
#pragma unroll
        for (int mi = 0; mi < 2; ++mi) {
            Ahf[mi] = *(const f16x8*)&Ah_s[cur][wm * 32 + mi * 16 + fr][fc * 8];
            if (ASPLIT == 2)
                Alf[mi] = *(const f16x8*)&Al_s[cur][wm * 32 + mi * 16 + fr][fc * 8];
        }
#pragma unroll
        for (int nj = 0; nj < 2; ++nj) {
            Bhf[nj] = *(const f16x8*)&Wh_s[cur][wn * 32 + nj * 16 + fr][fc * 8];
            if (WSPLIT)
                Blf[nj] = *(const f16x8*)&Wl_s[cur][wn * 32 + nj * 16 + fr][fc * 8];
        }
        __builtin_amdgcn_s_setprio(1);
#pragma unroll
        for (int mi = 0; mi < 2; ++mi)
#pragma unroll
            for (int nj = 0; nj < 2; ++nj) {
                acc[mi][nj] = __builtin_amdgcn_mfma_f32_16x16x32_f16(
                    Ahf[mi], Bhf[nj], acc[mi][nj], 0, 0, 0);
                if (WSPLIT)
                    acc[mi][nj] = __builtin_amdgcn_mfma_f32_16x16x32_f16(
                        Ahf[mi], Blf[nj], acc[mi][nj], 0, 0, 0);
                if (ASPLIT == 2)
                    acc[mi][nj] = __builtin_amdgcn_mfma_f32_16x16x32_f16(
                        Alf[mi], Bhf[nj], acc[mi][nj], 0, 0, 0);
            }
        __builtin_amdgcn_s_setprio(0);
        if (ks < 15) stage(cur ^ 1);
        __syncthreads();
        cur ^= 1;
    }

    if (SMODE == 0) {
        float* out = (float*)Out0;
#pragma unroll
        for (int mi = 0; mi < 2; ++mi)
#pragma unroll
            for (int nj = 0; nj < 2; ++nj)
#pragma unroll
                for (int r = 0; r < 4; ++r)
                    out[(size_t)(m0b + wm * 32 + mi * 16 + fc * 4 + r) * EE +
                        n0b + wn * 32 + nj * 16 + fr] = acc[mi][nj][r];
        return;
    }

    // ---- head-layout stores via LDS transpose ----
    __syncthreads();
#pragma unroll
    for (int mi = 0; mi < 2; ++mi)
#pragma unroll
        for (int nj = 0; nj < 2; ++nj)
#pragma unroll
            for (int r = 0; r < 4; ++r)
                Ep[wn * 32 + nj * 16 + fr][wm * 32 + mi * 16 + fc * 4 + r] =
                    (f16)acc[mi][nj][r];
    __syncthreads();
    if (SMODE == 1) {
        f16* dhi = (f16*)Out0;
#pragma unroll
        for (int i = 0; i < 2; ++i) {
            int task = t * 2 + i;               // (mr 0..63, h 0..7)
            int mr = task >> 3, h = task & 7;
            f16x8 v;
#pragma unroll
            for (int d = 0; d < 8; ++d) v[d] = Ep[8 * d + h][mr];
            *(f16x8*)&dhi[((size_t)h * BT + m0b + mr) * DD + (n0b >> 3)] = v;
        }
        __syncthreads();
#pragma unroll
        for (int mi = 0; mi < 2; ++mi)
#pragma unroll
            for (int nj = 0; nj < 2; ++nj)
#pragma unroll
                for (int r = 0; r < 4; ++r) {
                    float x = acc[mi][nj][r];
                    f16 hh = (f16)x;
                    Ep[wn * 32 + nj * 16 + fr][wm * 32 + mi * 16 + fc * 4 + r] =
                        (f16)(x - (float)hh);
                }
        __syncthreads();
#pragma unroll
        for (int i = 0; i < 2; ++i) {
            int task = t * 2 + i;
            int mr = task >> 3, h = task & 7;
            f16x8 v;
#pragma unroll
            for (int d = 0; d < 8; ++d) v[d] = Ep[8 * d + h][mr];
            *(f16x8*)&Out1[((size_t)h * BT + m0b + mr) * DD + (n0b >> 3)] = v;
        }
    } else {   // SMODE == 2: V^T planes [h][d][BT]
        f16* dst = (f16*)Out0;
#pragma unroll
        for (int i = 0; i < 2; ++i) {
            int task = t * 2 + i;               // (nn 0..63, mg 0..7)
            int mg = task & 7, nn = task >> 3;
            int h = nn & 7, dl = nn >> 3;
            f16x8 v = *(const f16x8*)&Ep[nn][mg * 8];
            *(f16x8*)&dst[((size_t)(h * DD + (n0b >> 3) + dl)) * BT +
                          m0b + mg * 8] = v;
        }
    }
}

// ---------------------------------------------------------------------------
// MFMA flash attention: 64-key tiles, double-buffered LDS + reg-staged
// prefetch, defer-max (THR=8). Block = 4 waves x 16 q rows. Grid (16,8,4).
// ---------------------------------------------------------------------------
__global__ __launch_bounds__(256) void attn_mfma_k(const f16* __restrict__ qhiP,
    const f16* __restrict__ qloP, const f16* __restrict__ khiP,
    const f16* __restrict__ kloP, const f16* __restrict__ vTP,
    f16* __restrict__ ctx) {
    __shared__ __align__(16) f16 Khi[2][64][64];   // XOR-swizzled 16B chunks
    __shared__ __align__(16) f16 Klo[2][64][64];
    __shared__ __align__(16) f16 VT[2][64][72];    // [d][key], padded
    __shared__ __align__(16) f16 Pl[4][16][88];    // per-wave P[q][key]

    const int t  = threadIdx.x;
    const int w  = t >> 6;
    const int l  = t & 63;
    const int lg = l >> 4;
    const int lq = l & 15;
    const int q0 = blockIdx.x * 64 + w * 16;
    const int h  = blockIdx.y;
    const int b  = blockIdx.z;
    const size_t plane = ((size_t)h * BT + (size_t)b * TT) * DD;

    f16x8 Qhi[2], Qlo[2];
#pragma unroll
    for (int kf = 0; kf < 2; ++kf) {
        size_t qo = plane + (size_t)(q0 + lq) * DD + kf * 32 + lg * 8;
        Qhi[kf] = *(const f16x8*)&qhiP[qo];
        Qlo[kf] = *(const f16x8*)&qloP[qo];
    }

    f32x4 Oacc[4];
#pragma unroll
    for (int i = 0; i < 4; ++i) Oacc[i] = f32x4{0.f, 0.f, 0.f, 0.f};
    float m = -1e30f, lsum = 0.f;

    const int sr = t >> 2, sch = t & 3;
    f16x8 kh[2], kl[2], vv[2];

    auto loadKV = [&](int kt0) {
        size_t off = plane + (size_t)(kt0 + sr) * DD + sch * 16;
        kh[0] = *(const f16x8*)&khiP[off];
        kh[1] = *(const f16x8*)&khiP[off + 8];
        kl[0] = *(const f16x8*)&kloP[off];
        kl[1] = *(const f16x8*)&kloP[off + 8];
        size_t voff = ((size_t)h * DD + sr) * BT + (size_t)b * TT + kt0 + sch * 16;
        vv[0] = *(const f16x8*)&vTP[voff];
        vv[1] = *(const f16x8*)&vTP[voff + 8];
    };
    auto stageKV = [&](int bf) {
#pragma unroll
        for (int i = 0; i < 2; ++i) {
            int chunk = sch * 2 + i;
            int dsw = chunk ^ (sr & 7);
            *(f16x8*)&Khi[bf][sr][dsw * 8] = kh[i];
            *(f16x8*)&Klo[bf][sr][dsw * 8] = kl[i];
            *(f16x8*)&VT[bf][sr][chunk * 8] = vv[i];
        }
    };

    loadKV(0);
    stageKV(0);
    __syncthreads();
    int cur = 0;

    for (int kt0 = 0; kt0 < TT; kt0 += 64) {
        if (kt0 + 64 < TT) loadKV(kt0 + 64);

        // ---- QK^T (swapped): S^T[key][q], 3-product split fp16 ----
        f32x4 Sc[4];
        __builtin_amdgcn_s_setprio(1);
#pragma unroll
        for (int kt = 0; kt < 4; ++kt) {
            f32x4 c = f32x4{0.f, 0.f, 0.f, 0.f};
            int keyr = kt * 16 + lq;
#pragma unroll
            for (int kf = 0; kf < 2; ++kf) {
                int dblk = kf * 4 + lg;
                int sw = dblk ^ (keyr & 7);
                f16x8 ahi = *(const f16x8*)&Khi[cur][keyr][sw * 8];
                f16x8 alo = *(const f16x8*)&Klo[cur][keyr][sw * 8];
                c = __builtin_amdgcn_mfma_f32_16x16x32_f16(ahi, Qhi[kf], c, 0, 0, 0);
                c = __builtin_amdgcn_mfma_f32_16x16x32_f16(ahi, Qlo[kf], c, 0, 0, 0);
                c = __builtin_amdgcn_mfma_f32_16x16x32_f16(alo, Qhi[kf], c, 0, 0, 0);
            }
            Sc[kt] = c;
        }
        __builtin_amdgcn_s_setprio(0);

        // ---- online softmax for q-row lq (16 keys/lane) ----
        float s[16];
#pragma unroll
        for (int kt = 0; kt < 4; ++kt)
#pragma unroll
            for (int r = 0; r < 4; ++r) s[kt * 4 + r] = Sc[kt][r];
        float tm = s[0];
#pragma unroll
        for (int i = 1; i < 16; ++i) tm = fmaxf(tm, s[i]);
        tm = fmaxf(tm, __shfl_xor(tm, 16));
        tm = fmaxf(tm, __shfl_xor(tm, 32));

        bool skip = __all(tm <= m + 8.0f);
        float Mn = m, corr = 1.0f;
        if (!skip) {
            Mn = fmaxf(m, tm);
            corr = __expf(m - Mn);
        }
        float ps = 0.f;
        f16 ph[16];
#pragma unroll
        for (int i = 0; i < 16; ++i) {
            float p = __expf(s[i] - Mn);
            ps += p;
            ph[i] = (f16)p;
        }
        ps += __shfl_xor(ps, 16);
        ps += __shfl_xor(ps, 32);
        if (skip) {
            lsum += ps;
        } else {
            lsum = lsum * corr + ps;
            m = Mn;
        }

        // ---- write P (fp16 packed pairs) ----
#pragma unroll
        for (int kt = 0; kt < 4; ++kt)
#pragma unroll
            for (int rp = 0; rp < 4; rp += 2) {
                union { f16 h; unsigned short u; } u0, u1;
                u0.h = ph[kt * 4 + rp]; u1.h = ph[kt * 4 + rp + 1];
                unsigned int pk = ((unsigned int)u1.u << 16) | u0.u;
                *(unsigned int*)&Pl[w][lq][kt * 16 + lg * 4 + rp] = pk;
            }

        if (!skip) {
            float cq[4];
#pragma unroll
            for (int r = 0; r < 4; ++r) cq[r] = __shfl(corr, lg * 4 + r);
#pragma unroll
            for (int dvt = 0; dvt < 4; ++dvt)
#pragma unroll
                for (int r = 0; r < 4; ++r) Oacc[dvt][r] *= cq[r];
        }

        // ---- PV: O += P @ V ----
        __builtin_amdgcn_s_setprio(1);
#pragma unroll
        for (int kf = 0; kf < 2; ++kf) {
            f16x8 pa = *(const f16x8*)&Pl[w][lq][kf * 32 + lg * 8];
#pragma unroll
            for (int dvt = 0; dvt < 4; ++dvt) {
                f16x8 bv = *(const f16x8*)&VT[cur][dvt * 16 + lq][kf * 32 + lg * 8];
                Oacc[dvt] = __builtin_amdgcn_mfma_f32_16x16x32_f16(pa, bv, Oacc[dvt], 0, 0, 0);
            }
        }
        __builtin_amdgcn_s_setprio(0);

        if (kt0 + 64 < TT) stageKV(cur ^ 1);
        __syncthreads();
        cur ^= 1;
    }

    float linv = 1.0f / lsum;
    float lq4[4];
#pragma unroll
    for (int r = 0; r < 4; ++r) lq4[r] = __shfl(linv, lg * 4 + r);
#pragma unroll
    for (int r = 0; r < 4; ++r) {
        f16* crow = ctx + (size_t)(b * TT + q0 + lg * 4 + r) * EE + h * DD;
#pragma unroll
        for (int dvt = 0; dvt < 4; ++dvt)
            crow[dvt * 16 + lq] = (f16)(Oacc[dvt][r] * lq4[r]);
    }
}

// ---------------------------------------------------------------------------
extern "C" void kernel_launch(void* const* d_in, const int* in_sizes, int n_in,
                              void* d_out, int out_size, void* d_ws, size_t ws_size,
                              hipStream_t stream) {
    const float* q  = (const float*)d_in[0];
    const float* kv = (const float*)d_in[1];
    const float* Wq = (const float*)d_in[2];
    const float* Wk = (const float*)d_in[3];
    const float* Wv = (const float*)d_in[4];
    const float* Wo = (const float*)d_in[5];
    float* out = (float*)d_out;

    f16* ws = (f16*)d_ws;
    const size_t PL  = (size_t)HH * BT * DD;   // 2,097,152 f16 per plane
    const size_t WPL = (size_t)EE * EE;
    f16* qhi = ws + 0 * PL;
    f16* qlo = ws + 1 * PL;
    f16* khi = ws + 2 * PL;
    f16* klo = ws + 3 * PL;
    f16* vT  = ws + 4 * PL;      // [H][64][BT]
    f16* ctx = ws + 5 * PL;      // [BT][512]
    f16* wqh = ws + 6 * PL;
    f16* wql = wqh + 1 * WPL;
    f16* wkh = wqh + 2 * WPL;
    f16* wkl = wqh + 3 * WPL;
    f16* wvh = wqh + 4 * WPL;
    f16* woh = wqh + 5 * WPL;

    prep_w_k<<<dim3((EE * EE) / 256, 4), dim3(256), 0, stream>>>(
        Wq, Wk, Wv, Wo, wqh, wql, wkh, wkl, wvh, woh);

    dim3 ggrid(BT / 64, EE / 64);   // (64, 8) = 512 blocks
    mm_k<2, 1, 1><<<ggrid, dim3(256), 0, stream>>>(q,  wqh, wql, qhi, qlo);
    mm_k<2, 1, 1><<<ggrid, dim3(256), 0, stream>>>(kv, wkh, wkl, khi, klo);
    mm_k<1, 0, 2><<<ggrid, dim3(256), 0, stream>>>(kv, wvh, nullptr, vT, nullptr);

    attn_mfma_k<<<dim3(TT / 64, HH, BB), dim3(256), 0, stream>>>(
        qhi, qlo, khi, klo, vT, ctx);

    mm_k<0, 0, 0><<<ggrid, dim3(256), 0, stream>>>(ctx, woh, nullptr, out, nullptr);
}

// Round 5
// 83.939 us; speedup vs baseline: 8.6965x; 1.1007x over previous
//
#include <hip/hip_runtime.h>
#include <math.h>

#define BB 4
#define TT 1024
#define EE 512
#define HH 8
#define DD 64
#define BT (BB * TT)   // 4096

typedef _Float16 f16;
typedef __attribute__((ext_vector_type(8))) _Float16 f16x8;
typedef __attribute__((ext_vector_type(4))) float f32x4;

// ---------------------------------------------------------------------------
// Prep weights: transposed fp16 planes WT[n][k].
//  which=0: Wq * 512, hi+lo   which=1: Wk col-permuted, hi+lo
//  which=2: Wv hi only        which=3: Wo hi only
// ---------------------------------------------------------------------------
__global__ __launch_bounds__(256) void prep_w_k(const float* __restrict__ Wq,
    const float* __restrict__ Wk, const float* __restrict__ Wv,
    const float* __restrict__ Wo,
    f16* __restrict__ wqh, f16* __restrict__ wql,
    f16* __restrict__ wkh, f16* __restrict__ wkl,
    f16* __restrict__ wvh, f16* __restrict__ woh) {
    int idx = blockIdx.x * 256 + threadIdx.x;   // 512*512
    int k = idx & (EE - 1);
    int n = idx >> 9;
    int which = blockIdx.y;
    if (which == 0) {
        float v = Wq[k * EE + n] * 512.0f;      // fold dk*D scale (exact pow2)
        f16 hi = (f16)v;
        wqh[n * EE + k] = hi;
        wql[n * EE + k] = (f16)(v - (float)hi);
    } else if (which == 1) {
        int d = n >> 3, h = n & 7;
        int sn = (((DD - d) & (DD - 1)) << 3) | h;  // K'[.,d] = K[.,(D-d)%D]
        float v = Wk[k * EE + sn];
        f16 hi = (f16)v;
        wkh[n * EE + k] = hi;
        wkl[n * EE + k] = (f16)(v - (float)hi);
    } else if (which == 2) {
        wvh[n * EE + k] = (f16)Wv[k * EE + n];
    } else {
        woh[n * EE + k] = (f16)Wo[k * EE + n];
    }
}

// ---------------------------------------------------------------------------
// Fused projection kernel. Grid (BT/64, EE/64, 2), block 256 (4 waves).
// z=0: Q = q @ Wq' -> split head planes (qhi,qlo).
// z=1: K' = kv @ Wk' -> split head planes (khi,klo)  AND  V = kv @ Wv -> vT.
// Tile 64x64, BK=32, double-buffered LDS + reg-staged prefetch, 1 barrier/step.
// A is fp32 -> hi/lo split once, shared by K (3-product) and V (1-product).
// ---------------------------------------------------------------------------
__global__ __launch_bounds__(256) void proj_k(
    const float* __restrict__ qA, const float* __restrict__ kvA,
    const f16* __restrict__ wqh, const f16* __restrict__ wql,
    const f16* __restrict__ wkh, const f16* __restrict__ wkl,
    const f16* __restrict__ wvh,
    f16* __restrict__ qhi, f16* __restrict__ qlo,
    f16* __restrict__ khi, f16* __restrict__ klo, f16* __restrict__ vT) {
    __shared__ __align__(16) f16 Ah_s[2][64][40];
    __shared__ __align__(16) f16 Al_s[2][64][40];
    __shared__ __align__(16) f16 Wh_s[2][64][40];
    __shared__ __align__(16) f16 Wl_s[2][64][40];
    __shared__ __align__(16) f16 Wv_s[2][64][40];
    __shared__ __align__(16) f16 Ep[64][72];

    const int t = threadIdx.x;
    const int w = t >> 6, l = t & 63;
    const int wm = w >> 1, wn = w & 1;
    const int fr = l & 15, fc = l >> 4;
    const int m0b = blockIdx.x * 64;
    const int n0b = blockIdx.y * 64;
    const int z   = blockIdx.z;
    const int sr = t >> 2, sch = t & 3;

    const float* A  = z ? kvA : qA;
    const f16*   WH = z ? wkh : wqh;
    const f16*   WL = z ? wkl : wql;

    f32x4 accK[2][2], accV[2][2];
#pragma unroll
    for (int i = 0; i < 2; ++i)
#pragma unroll
        for (int j = 0; j < 2; ++j) {
            accK[i][j] = f32x4{0.f, 0.f, 0.f, 0.f};
            accV[i][j] = f32x4{0.f, 0.f, 0.f, 0.f};
        }

    float4 a4x[2];
    f16x8 wh8, wl8, wv8;

    auto loadAB = [&](int k0) {
        const float* src = A + (size_t)(m0b + sr) * EE + k0 + sch * 8;
        a4x[0] = ((const float4*)src)[0];
        a4x[1] = ((const float4*)src)[1];
        wh8 = *(const f16x8*)&WH[(size_t)(n0b + sr) * EE + k0 + sch * 8];
        wl8 = *(const f16x8*)&WL[(size_t)(n0b + sr) * EE + k0 + sch * 8];
        if (z) wv8 = *(const f16x8*)&wvh[(size_t)(n0b + sr) * EE + k0 + sch * 8];
    };
    auto stage = [&](int bf) {
        float xs[8] = {a4x[0].x, a4x[0].y, a4x[0].z, a4x[0].w,
                       a4x[1].x, a4x[1].y, a4x[1].z, a4x[1].w};
        f16x8 hi, lo;
#pragma unroll
        for (int e = 0; e < 8; ++e) {
            f16 hh = (f16)xs[e];
            hi[e] = hh;
            lo[e] = (f16)(xs[e] - (float)hh);
        }
        *(f16x8*)&Ah_s[bf][sr][sch * 8] = hi;
        *(f16x8*)&Al_s[bf][sr][sch * 8] = lo;
        *(f16x8*)&Wh_s[bf][sr][sch * 8] = wh8;
        *(f16x8*)&Wl_s[bf][sr][sch * 8] = wl8;
        if (z) *(f16x8*)&Wv_s[bf][sr][sch * 8] = wv8;
    };

    loadAB(0);
    stage(0);
    __syncthreads();
    int cur = 0;
    for (int ks = 0; ks < 16; ++ks) {
        if (ks < 15) loadAB((ks + 1) * 32);
        f16x8 Ahf[2], Alf[2], Bh[2], Bl[2], Bv[2];
#pragma unroll
        for (int mi = 0; mi < 2; ++mi) {
            Ahf[mi] = *(const f16x8*)&Ah_s[cur][wm * 32 + mi * 16 + fr][fc * 8];
            Alf[mi] = *(const f16x8*)&Al_s[cur][wm * 32 + mi * 16 + fr][fc * 8];
        }
#pragma unroll
        for (int nj = 0; nj < 2; ++nj) {
            Bh[nj] = *(const f16x8*)&Wh_s[cur][wn * 32 + nj * 16 + fr][fc * 8];
            Bl[nj] = *(const f16x8*)&Wl_s[cur][wn * 32 + nj * 16 + fr][fc * 8];
            if (z) Bv[nj] = *(const f16x8*)&Wv_s[cur][wn * 32 + nj * 16 + fr][fc * 8];
        }
        __builtin_amdgcn_s_setprio(1);
#pragma unroll
        for (int mi = 0; mi < 2; ++mi)
#pragma unroll
            for (int nj = 0; nj < 2; ++nj) {
                accK[mi][nj] = __builtin_amdgcn_mfma_f32_16x16x32_f16(
                    Ahf[mi], Bh[nj], accK[mi][nj], 0, 0, 0);
                accK[mi][nj] = __builtin_amdgcn_mfma_f32_16x16x32_f16(
                    Ahf[mi], Bl[nj], accK[mi][nj], 0, 0, 0);
                accK[mi][nj] = __builtin_amdgcn_mfma_f32_16x16x32_f16(
                    Alf[mi], Bh[nj], accK[mi][nj], 0, 0, 0);
                if (z)
                    accV[mi][nj] = __builtin_amdgcn_mfma_f32_16x16x32_f16(
                        Ahf[mi], Bv[nj], accV[mi][nj], 0, 0, 0);
            }
        __builtin_amdgcn_s_setprio(0);
        if (ks < 15) stage(cur ^ 1);
        __syncthreads();
        cur ^= 1;
    }

    // ---- epilogue: hi plane (Q or K) via LDS transpose ----
    f16* dsthi = z ? khi : qhi;
    f16* dstlo = z ? klo : qlo;
#pragma unroll
    for (int mi = 0; mi < 2; ++mi)
#pragma unroll
        for (int nj = 0; nj < 2; ++nj)
#pragma unroll
            for (int r = 0; r < 4; ++r)
                Ep[wn * 32 + nj * 16 + fr][wm * 32 + mi * 16 + fc * 4 + r] =
                    (f16)accK[mi][nj][r];
    __syncthreads();
#pragma unroll
    for (int i = 0; i < 2; ++i) {
        int task = t * 2 + i;               // (mr 0..63, h 0..7)
        int mr = task >> 3, h = task & 7;
        f16x8 v;
#pragma unroll
        for (int d = 0; d < 8; ++d) v[d] = Ep[8 * d + h][mr];
        *(f16x8*)&dsthi[((size_t)h * BT + m0b + mr) * DD + (n0b >> 3)] = v;
    }
    __syncthreads();
    // ---- lo plane ----
#pragma unroll
    for (int mi = 0; mi < 2; ++mi)
#pragma unroll
        for (int nj = 0; nj < 2; ++nj)
#pragma unroll
            for (int r = 0; r < 4; ++r) {
                float x = accK[mi][nj][r];
                f16 hh = (f16)x;
                Ep[wn * 32 + nj * 16 + fr][wm * 32 + mi * 16 + fc * 4 + r] =
                    (f16)(x - (float)hh);
            }
    __syncthreads();
#pragma unroll
    for (int i = 0; i < 2; ++i) {
        int task = t * 2 + i;
        int mr = task >> 3, h = task & 7;
        f16x8 v;
#pragma unroll
        for (int d = 0; d < 8; ++d) v[d] = Ep[8 * d + h][mr];
        *(f16x8*)&dstlo[((size_t)h * BT + m0b + mr) * DD + (n0b >> 3)] = v;
    }
    if (z) {
        // ---- V plane: vT[h][d][BT] ----
        __syncthreads();
#pragma unroll
        for (int mi = 0; mi < 2; ++mi)
#pragma unroll
            for (int nj = 0; nj < 2; ++nj)
#pragma unroll
                for (int r = 0; r < 4; ++r)
                    Ep[wn * 32 + nj * 16 + fr][wm * 32 + mi * 16 + fc * 4 + r] =
                        (f16)accV[mi][nj][r];
        __syncthreads();
#pragma unroll
        for (int i = 0; i < 2; ++i) {
            int task = t * 2 + i;               // (nn 0..63, mg 0..7)
            int mg = task & 7, nn = task >> 3;
            int h = nn & 7, dl = nn >> 3;
            f16x8 v = *(const f16x8*)&Ep[nn][mg * 8];
            *(f16x8*)&vT[((size_t)(h * DD + (n0b >> 3) + dl)) * BT +
                         m0b + mg * 8] = v;
        }
    }
}

// ---------------------------------------------------------------------------
// Output GEMM: out = ctx(f16) @ Wo (f16) -> fp32. Tile 64x64, BK=64,
// double-buffered LDS + reg prefetch: 8 steps x 8 MFMA/wave, 1 barrier/step.
// ---------------------------------------------------------------------------
__global__ __launch_bounds__(256) void outmm_k(const f16* __restrict__ Af,
                                               const f16* __restrict__ WThi,
                                               float* __restrict__ out) {
    __shared__ __align__(16) f16 Ah_s[2][64][72];
    __shared__ __align__(16) f16 Wh_s[2][64][72];

    const int t = threadIdx.x;
    const int w = t >> 6, l = t & 63;
    const int wm = w >> 1, wn = w & 1;
    const int fr = l & 15, fc = l >> 4;
    const int m0b = blockIdx.x * 64;
    const int n0b = blockIdx.y * 64;
    const int sr = t >> 2, sch = t & 3;

    f32x4 acc[2][2];
#pragma unroll
    for (int i = 0; i < 2; ++i)
#pragma unroll
        for (int j = 0; j < 2; ++j) acc[i][j] = f32x4{0.f, 0.f, 0.f, 0.f};

    f16x8 af[2], wf[2];
    auto loadAB = [&](int k0) {
#pragma unroll
        for (int i = 0; i < 2; ++i) {
            af[i] = *(const f16x8*)&Af[(size_t)(m0b + sr) * EE + k0 + sch * 16 + i * 8];
            wf[i] = *(const f16x8*)&WThi[(size_t)(n0b + sr) * EE + k0 + sch * 16 + i * 8];
        }
    };
    auto stage = [&](int bf) {
#pragma unroll
        for (int i = 0; i < 2; ++i) {
            *(f16x8*)&Ah_s[bf][sr][sch * 16 + i * 8] = af[i];
            *(f16x8*)&Wh_s[bf][sr][sch * 16 + i * 8] = wf[i];
        }
    };

    loadAB(0);
    stage(0);
    __syncthreads();
    int cur = 0;
    for (int ks = 0; ks < 8; ++ks) {
        if (ks < 7) loadAB((ks + 1) * 64);
        f16x8 Ahf[2][2], Bhf[2][2];
#pragma unroll
        for (int mi = 0; mi < 2; ++mi)
#pragma unroll
            for (int kb = 0; kb < 2; ++kb)
                Ahf[mi][kb] =
                    *(const f16x8*)&Ah_s[cur][wm * 32 + mi * 16 + fr][kb * 32 + fc * 8];
#pragma unroll
        for (int nj = 0; nj < 2; ++nj)
#pragma unroll
            for (int kb = 0; kb < 2; ++kb)
                Bhf[nj][kb] =
                    *(const f16x8*)&Wh_s[cur][wn * 32 + nj * 16 + fr][kb * 32 + fc * 8];
        __builtin_amdgcn_s_setprio(1);
#pragma unroll
        for (int mi = 0; mi < 2; ++mi)
#pragma unroll
            for (int nj = 0; nj < 2; ++nj)
#pragma unroll
                for (int kb = 0; kb < 2; ++kb)
                    acc[mi][nj] = __builtin_amdgcn_mfma_f32_16x16x32_f16(
                        Ahf[mi][kb], Bhf[nj][kb], acc[mi][nj], 0, 0, 0);
        __builtin_amdgcn_s_setprio(0);
        if (ks < 7) stage(cur ^ 1);
        __syncthreads();
        cur ^= 1;
    }

    float* o = out;
#pragma unroll
    for (int mi = 0; mi < 2; ++mi)
#pragma unroll
        for (int nj = 0; nj < 2; ++nj)
#pragma unroll
            for (int r = 0; r < 4; ++r)
                o[(size_t)(m0b + wm * 32 + mi * 16 + fc * 4 + r) * EE +
                  n0b + wn * 32 + nj * 16 + fr] = acc[mi][nj][r];
}

// ---------------------------------------------------------------------------
// MFMA flash attention: 64-key tiles, double-buffered LDS + reg-staged
// prefetch, defer-max (THR=8). Block = 4 waves x 16 q rows. Grid (16,8,4).
// ---------------------------------------------------------------------------
__global__ __launch_bounds__(256) void attn_mfma_k(const f16* __restrict__ qhiP,
    const f16* __restrict__ qloP, const f16* __restrict__ khiP,
    const f16* __restrict__ kloP, const f16* __restrict__ vTP,
    f16* __restrict__ ctx) {
    __shared__ __align__(16) f16 Khi[2][64][64];   // XOR-swizzled 16B chunks
    __shared__ __align__(16) f16 Klo[2][64][64];
    __shared__ __align__(16) f16 VT[2][64][72];    // [d][key], padded
    __shared__ __align__(16) f16 Pl[4][16][88];    // per-wave P[q][key]

    const int t  = threadIdx.x;
    const int w  = t >> 6;
    const int l  = t & 63;
    const int lg = l >> 4;
    const int lq = l & 15;
    const int q0 = blockIdx.x * 64 + w * 16;
    const int h  = blockIdx.y;
    const int b  = blockIdx.z;
    const size_t plane = ((size_t)h * BT + (size_t)b * TT) * DD;

    f16x8 Qhi[2], Qlo[2];
#pragma unroll
    for (int kf = 0; kf < 2; ++kf) {
        size_t qo = plane + (size_t)(q0 + lq) * DD + kf * 32 + lg * 8;
        Qhi[kf] = *(const f16x8*)&qhiP[qo];
        Qlo[kf] = *(const f16x8*)&qloP[qo];
    }

    f32x4 Oacc[4];
#pragma unroll
    for (int i = 0; i < 4; ++i) Oacc[i] = f32x4{0.f, 0.f, 0.f, 0.f};
    float m = -1e30f, lsum = 0.f;

    const int sr = t >> 2, sch = t & 3;
    f16x8 kh[2], kl[2], vv[2];

    auto loadKV = [&](int kt0) {
        size_t off = plane + (size_t)(kt0 + sr) * DD + sch * 16;
        kh[0] = *(const f16x8*)&khiP[off];
        kh[1] = *(const f16x8*)&khiP[off + 8];
        kl[0] = *(const f16x8*)&kloP[off];
        kl[1] = *(const f16x8*)&kloP[off + 8];
        size_t voff = ((size_t)h * DD + sr) * BT + (size_t)b * TT + kt0 + sch * 16;
        vv[0] = *(const f16x8*)&vTP[voff];
        vv[1] = *(const f16x8*)&vTP[voff + 8];
    };
    auto stageKV = [&](int bf) {
#pragma unroll
        for (int i = 0; i < 2; ++i) {
            int chunk = sch * 2 + i;
            int dsw = chunk ^ (sr & 7);
            *(f16x8*)&Khi[bf][sr][dsw * 8] = kh[i];
            *(f16x8*)&Klo[bf][sr][dsw * 8] = kl[i];
            *(f16x8*)&VT[bf][sr][chunk * 8] = vv[i];
        }
    };

    loadKV(0);
    stageKV(0);
    __syncthreads();
    int cur = 0;

    for (int kt0 = 0; kt0 < TT; kt0 += 64) {
        if (kt0 + 64 < TT) loadKV(kt0 + 64);

        // ---- QK^T (swapped): S^T[key][q], 3-product split fp16 ----
        f32x4 Sc[4];
        __builtin_amdgcn_s_setprio(1);
#pragma unroll
        for (int kt = 0; kt < 4; ++kt) {
            f32x4 c = f32x4{0.f, 0.f, 0.f, 0.f};
            int keyr = kt * 16 + lq;
#pragma unroll
            for (int kf = 0; kf < 2; ++kf) {
                int dblk = kf * 4 + lg;
                int sw = dblk ^ (keyr & 7);
                f16x8 ahi = *(const f16x8*)&Khi[cur][keyr][sw * 8];
                f16x8 alo = *(const f16x8*)&Klo[cur][keyr][sw * 8];
                c = __builtin_amdgcn_mfma_f32_16x16x32_f16(ahi, Qhi[kf], c, 0, 0, 0);
                c = __builtin_amdgcn_mfma_f32_16x16x32_f16(ahi, Qlo[kf], c, 0, 0, 0);
                c = __builtin_amdgcn_mfma_f32_16x16x32_f16(alo, Qhi[kf], c, 0, 0, 0);
            }
            Sc[kt] = c;
        }
        __builtin_amdgcn_s_setprio(0);

        // ---- online softmax for q-row lq (16 keys/lane) ----
        float s[16];
#pragma unroll
        for (int kt = 0; kt < 4; ++kt)
#pragma unroll
            for (int r = 0; r < 4; ++r) s[kt * 4 + r] = Sc[kt][r];
        float tm = s[0];
#pragma unroll
        for (int i = 1; i < 16; ++i) tm = fmaxf(tm, s[i]);
        tm = fmaxf(tm, __shfl_xor(tm, 16));
        tm = fmaxf(tm, __shfl_xor(tm, 32));

        bool skip = __all(tm <= m + 8.0f);
        float Mn = m, corr = 1.0f;
        if (!skip) {
            Mn = fmaxf(m, tm);
            corr = __expf(m - Mn);
        }
        float ps = 0.f;
        f16 ph[16];
#pragma unroll
        for (int i = 0; i < 16; ++i) {
            float p = __expf(s[i] - Mn);
            ps += p;
            ph[i] = (f16)p;
        }
        ps += __shfl_xor(ps, 16);
        ps += __shfl_xor(ps, 32);
        if (skip) {
            lsum += ps;
        } else {
            lsum = lsum * corr + ps;
            m = Mn;
        }

        // ---- write P (fp16 packed pairs) ----
#pragma unroll
        for (int kt = 0; kt < 4; ++kt)
#pragma unroll
            for (int rp = 0; rp < 4; rp += 2) {
                union { f16 h; unsigned short u; } u0, u1;
                u0.h = ph[kt * 4 + rp]; u1.h = ph[kt * 4 + rp + 1];
                unsigned int pk = ((unsigned int)u1.u << 16) | u0.u;
                *(unsigned int*)&Pl[w][lq][kt * 16 + lg * 4 + rp] = pk;
            }

        if (!skip) {
            float cq[4];
#pragma unroll
            for (int r = 0; r < 4; ++r) cq[r] = __shfl(corr, lg * 4 + r);
#pragma unroll
            for (int dvt = 0; dvt < 4; ++dvt)
#pragma unroll
                for (int r = 0; r < 4; ++r) Oacc[dvt][r] *= cq[r];
        }

        // ---- PV: O += P @ V ----
        __builtin_amdgcn_s_setprio(1);
#pragma unroll
        for (int kf = 0; kf < 2; ++kf) {
            f16x8 pa = *(const f16x8*)&Pl[w][lq][kf * 32 + lg * 8];
#pragma unroll
            for (int dvt = 0; dvt < 4; ++dvt) {
                f16x8 bv = *(const f16x8*)&VT[cur][dvt * 16 + lq][kf * 32 + lg * 8];
                Oacc[dvt] = __builtin_amdgcn_mfma_f32_16x16x32_f16(pa, bv, Oacc[dvt], 0, 0, 0);
            }
        }
        __builtin_amdgcn_s_setprio(0);

        if (kt0 + 64 < TT) stageKV(cur ^ 1);
        __syncthreads();
        cur ^= 1;
    }

    float linv = 1.0f / lsum;
    float lq4[4];
#pragma unroll
    for (int r = 0; r < 4; ++r) lq4[r] = __shfl(linv, lg * 4 + r);
#pragma unroll
    for (int r = 0; r < 4; ++r) {
        f16* crow = ctx + (size_t)(b * TT + q0 + lg * 4 + r) * EE + h * DD;
#pragma unroll
        for (int dvt = 0; dvt < 4; ++dvt)
            crow[dvt * 16 + lq] = (f16)(Oacc[dvt][r] * lq4[r]);
    }
}

// ---------------------------------------------------------------------------
extern "C" void kernel_launch(void* const* d_in, const int* in_sizes, int n_in,
                              void* d_out, int out_size, void* d_ws, size_t ws_size,
                              hipStream_t stream) {
    const float* q  = (const float*)d_in[0];
    const float* kv = (const float*)d_in[1];
    const float* Wq = (const float*)d_in[2];
    const float* Wk = (const float*)d_in[3];
    const float* Wv = (const float*)d_in[4];
    const float* Wo = (const float*)d_in[5];
    float* out = (float*)d_out;

    f16* ws = (f16*)d_ws;
    const size_t PL  = (size_t)HH * BT * DD;   // 2,097,152 f16 per plane
    const size_t WPL = (size_t)EE * EE;
    f16* qhi = ws + 0 * PL;
    f16* qlo = ws + 1 * PL;
    f16* khi = ws + 2 * PL;
    f16* klo = ws + 3 * PL;
    f16* vT  = ws + 4 * PL;      // [H][64][BT]
    f16* ctx = ws + 5 * PL;      // [BT][512]
    f16* wqh = ws + 6 * PL;
    f16* wql = wqh + 1 * WPL;
    f16* wkh = wqh + 2 * WPL;
    f16* wkl = wqh + 3 * WPL;
    f16* wvh = wqh + 4 * WPL;
    f16* woh = wqh + 5 * WPL;

    prep_w_k<<<dim3((EE * EE) / 256, 4), dim3(256), 0, stream>>>(
        Wq, Wk, Wv, Wo, wqh, wql, wkh, wkl, wvh, woh);

    proj_k<<<dim3(BT / 64, EE / 64, 2), dim3(256), 0, stream>>>(
        q, kv, wqh, wql, wkh, wkl, wvh, qhi, qlo, khi, klo, vT);

    attn_mfma_k<<<dim3(TT / 64, HH, BB), dim3(256), 0, stream>>>(
        qhi, qlo, khi, klo, vT, ctx);

    outmm_k<<<dim3(BT / 64, EE / 64), dim3(256), 0, stream>>>(ctx, woh, out);
}

// Round 6
// 78.313 us; speedup vs baseline: 9.3213x; 1.0718x over previous
//
#include <hip/hip_runtime.h>
#include <math.h>

#define BB 4
#define TT 1024
#define EE 512
#define HH 8
#define DD 64
#define BT (BB * TT)   // 4096

typedef _Float16 f16;
typedef __attribute__((ext_vector_type(8))) _Float16 f16x8;
typedef __attribute__((ext_vector_type(4))) float f32x4;

// ---------------------------------------------------------------------------
// Prep weights: transposed fp16 planes WT[n][k].
// ---------------------------------------------------------------------------
__global__ __launch_bounds__(256) void prep_w_k(const float* __restrict__ Wq,
    const float* __restrict__ Wk, const float* __restrict__ Wv,
    const float* __restrict__ Wo,
    f16* __restrict__ wqh, f16* __restrict__ wql,
    f16* __restrict__ wkh, f16* __restrict__ wkl,
    f16* __restrict__ wvh, f16* __restrict__ woh) {
    int idx = blockIdx.x * 256 + threadIdx.x;   // 512*512
    int k = idx & (EE - 1);
    int n = idx >> 9;
    int which = blockIdx.y;
    if (which == 0) {
        float v = Wq[k * EE + n] * 512.0f;      // fold dk*D scale (exact pow2)
        f16 hi = (f16)v;
        wqh[n * EE + k] = hi;
        wql[n * EE + k] = (f16)(v - (float)hi);
    } else if (which == 1) {
        int d = n >> 3, h = n & 7;
        int sn = (((DD - d) & (DD - 1)) << 3) | h;  // K'[.,d] = K[.,(D-d)%D]
        float v = Wk[k * EE + sn];
        f16 hi = (f16)v;
        wkh[n * EE + k] = hi;
        wkl[n * EE + k] = (f16)(v - (float)hi);
    } else if (which == 2) {
        wvh[n * EE + k] = (f16)Wv[k * EE + n];
    } else {
        woh[n * EE + k] = (f16)Wo[k * EE + n];
    }
}

// ---------------------------------------------------------------------------
// Fused projection kernel. Grid (BT/128, EE/64, 2), block 256 (4 waves).
// z=0: Q = q @ Wq' -> split head planes.  z=1: K' and V from kv.
// Tile 128x64, BK=32, dbuf LDS + reg prefetch. Per-wave output 64x32
// (4 m-frags x 2 n-frags) -> 24-32 MFMA per step vs 12-14 ds_reads.
// ---------------------------------------------------------------------------
__global__ __launch_bounds__(256) void proj_k(
    const float* __restrict__ qA, const float* __restrict__ kvA,
    const f16* __restrict__ wqh, const f16* __restrict__ wql,
    const f16* __restrict__ wkh, const f16* __restrict__ wkl,
    const f16* __restrict__ wvh,
    f16* __restrict__ qhi, f16* __restrict__ qlo,
    f16* __restrict__ khi, f16* __restrict__ klo, f16* __restrict__ vT) {
    __shared__ __align__(16) f16 Ah_s[2][128][40];
    __shared__ __align__(16) f16 Al_s[2][128][40];
    __shared__ __align__(16) f16 Wh_s[2][64][40];
    __shared__ __align__(16) f16 Wl_s[2][64][40];
    __shared__ __align__(16) f16 Wv_s[2][64][40];
    // epilogue transpose buffer aliases the (dead) A double-buffer
    f16 (*Ep)[136] = reinterpret_cast<f16(*)[136]>(&Ah_s[0][0][0]);

    const int t = threadIdx.x;
    const int w = t >> 6, l = t & 63;
    const int wm = w >> 1, wn = w & 1;
    const int fr = l & 15, fc = l >> 4;
    const int m0b = blockIdx.x * 128;
    const int n0b = blockIdx.y * 64;
    const int z   = blockIdx.z;
    const int ar = t >> 1, ak = t & 1;      // A staging: row, k-half
    const int wr = t >> 2, wc = t & 3;      // W staging: row, chunk

    const float* A  = z ? kvA : qA;
    const f16*   WH = z ? wkh : wqh;
    const f16*   WL = z ? wkl : wql;

    f32x4 accK[4][2], accV[4][2];
#pragma unroll
    for (int i = 0; i < 4; ++i)
#pragma unroll
        for (int j = 0; j < 2; ++j) {
            accK[i][j] = f32x4{0.f, 0.f, 0.f, 0.f};
            accV[i][j] = f32x4{0.f, 0.f, 0.f, 0.f};
        }

    float4 a4x[4];
    f16x8 wh8, wl8, wv8;

    auto loadAB = [&](int k0) {
        const float* src = A + (size_t)(m0b + ar) * EE + k0 + ak * 16;
        a4x[0] = ((const float4*)src)[0];
        a4x[1] = ((const float4*)src)[1];
        a4x[2] = ((const float4*)src)[2];
        a4x[3] = ((const float4*)src)[3];
        wh8 = *(const f16x8*)&WH[(size_t)(n0b + wr) * EE + k0 + wc * 8];
        wl8 = *(const f16x8*)&WL[(size_t)(n0b + wr) * EE + k0 + wc * 8];
        if (z) wv8 = *(const f16x8*)&wvh[(size_t)(n0b + wr) * EE + k0 + wc * 8];
    };
    auto stage = [&](int bf) {
        float xs[16] = {a4x[0].x, a4x[0].y, a4x[0].z, a4x[0].w,
                        a4x[1].x, a4x[1].y, a4x[1].z, a4x[1].w,
                        a4x[2].x, a4x[2].y, a4x[2].z, a4x[2].w,
                        a4x[3].x, a4x[3].y, a4x[3].z, a4x[3].w};
        f16x8 hi0, hi1, lo0, lo1;
#pragma unroll
        for (int e = 0; e < 8; ++e) {
            f16 ha = (f16)xs[e];     hi0[e] = ha; lo0[e] = (f16)(xs[e] - (float)ha);
            f16 hb = (f16)xs[8 + e]; hi1[e] = hb; lo1[e] = (f16)(xs[8 + e] - (float)hb);
        }
        *(f16x8*)&Ah_s[bf][ar][ak * 16]     = hi0;
        *(f16x8*)&Ah_s[bf][ar][ak * 16 + 8] = hi1;
        *(f16x8*)&Al_s[bf][ar][ak * 16]     = lo0;
        *(f16x8*)&Al_s[bf][ar][ak * 16 + 8] = lo1;
        *(f16x8*)&Wh_s[bf][wr][wc * 8] = wh8;
        *(f16x8*)&Wl_s[bf][wr][wc * 8] = wl8;
        if (z) *(f16x8*)&Wv_s[bf][wr][wc * 8] = wv8;
    };

    loadAB(0);
    stage(0);
    __syncthreads();
    int cur = 0;
    for (int ks = 0; ks < 16; ++ks) {
        if (ks < 15) loadAB((ks + 1) * 32);
        f16x8 Ahf[4], Alf[4], Bh[2], Bl[2], Bv[2];
#pragma unroll
        for (int mi = 0; mi < 4; ++mi) {
            Ahf[mi] = *(const f16x8*)&Ah_s[cur][wm * 64 + mi * 16 + fr][fc * 8];
            Alf[mi] = *(const f16x8*)&Al_s[cur][wm * 64 + mi * 16 + fr][fc * 8];
        }
#pragma unroll
        for (int nj = 0; nj < 2; ++nj) {
            Bh[nj] = *(const f16x8*)&Wh_s[cur][wn * 32 + nj * 16 + fr][fc * 8];
            Bl[nj] = *(const f16x8*)&Wl_s[cur][wn * 32 + nj * 16 + fr][fc * 8];
            if (z) Bv[nj] = *(const f16x8*)&Wv_s[cur][wn * 32 + nj * 16 + fr][fc * 8];
        }
        __builtin_amdgcn_s_setprio(1);
#pragma unroll
        for (int mi = 0; mi < 4; ++mi)
#pragma unroll
            for (int nj = 0; nj < 2; ++nj) {
                accK[mi][nj] = __builtin_amdgcn_mfma_f32_16x16x32_f16(
                    Ahf[mi], Bh[nj], accK[mi][nj], 0, 0, 0);
                accK[mi][nj] = __builtin_amdgcn_mfma_f32_16x16x32_f16(
                    Ahf[mi], Bl[nj], accK[mi][nj], 0, 0, 0);
                accK[mi][nj] = __builtin_amdgcn_mfma_f32_16x16x32_f16(
                    Alf[mi], Bh[nj], accK[mi][nj], 0, 0, 0);
                if (z)
                    accV[mi][nj] = __builtin_amdgcn_mfma_f32_16x16x32_f16(
                        Ahf[mi], Bv[nj], accV[mi][nj], 0, 0, 0);
            }
        __builtin_amdgcn_s_setprio(0);
        if (ks < 15) stage(cur ^ 1);
        __syncthreads();
        cur ^= 1;
    }

    // ---- epilogue (Ep aliases dead LDS): hi plane via transpose ----
    f16* dsthi = z ? khi : qhi;
    f16* dstlo = z ? klo : qlo;
#pragma unroll
    for (int mi = 0; mi < 4; ++mi)
#pragma unroll
        for (int nj = 0; nj < 2; ++nj)
#pragma unroll
            for (int r = 0; r < 4; ++r)
                Ep[wn * 32 + nj * 16 + fr][wm * 64 + mi * 16 + fc * 4 + r] =
                    (f16)accK[mi][nj][r];
    __syncthreads();
#pragma unroll
    for (int i = 0; i < 4; ++i) {
        int task = t * 4 + i;               // (mr 0..127, h 0..7)
        int mr = task >> 3, h = task & 7;
        f16x8 v;
#pragma unroll
        for (int d = 0; d < 8; ++d) v[d] = Ep[8 * d + h][mr];
        *(f16x8*)&dsthi[((size_t)h * BT + m0b + mr) * DD + (n0b >> 3)] = v;
    }
    __syncthreads();
    // ---- lo plane ----
#pragma unroll
    for (int mi = 0; mi < 4; ++mi)
#pragma unroll
        for (int nj = 0; nj < 2; ++nj)
#pragma unroll
            for (int r = 0; r < 4; ++r) {
                float x = accK[mi][nj][r];
                f16 hh = (f16)x;
                Ep[wn * 32 + nj * 16 + fr][wm * 64 + mi * 16 + fc * 4 + r] =
                    (f16)(x - (float)hh);
            }
    __syncthreads();
#pragma unroll
    for (int i = 0; i < 4; ++i) {
        int task = t * 4 + i;
        int mr = task >> 3, h = task & 7;
        f16x8 v;
#pragma unroll
        for (int d = 0; d < 8; ++d) v[d] = Ep[8 * d + h][mr];
        *(f16x8*)&dstlo[((size_t)h * BT + m0b + mr) * DD + (n0b >> 3)] = v;
    }
    if (z) {
        // ---- V plane: vT[h][d][BT] ----
        __syncthreads();
#pragma unroll
        for (int mi = 0; mi < 4; ++mi)
#pragma unroll
            for (int nj = 0; nj < 2; ++nj)
#pragma unroll
                for (int r = 0; r < 4; ++r)
                    Ep[wn * 32 + nj * 16 + fr][wm * 64 + mi * 16 + fc * 4 + r] =
                        (f16)accV[mi][nj][r];
        __syncthreads();
#pragma unroll
        for (int i = 0; i < 4; ++i) {
            int task = t * 4 + i;           // (nn 0..63, mg 0..15)
            int mg = task & 15, nn = task >> 4;
            int h = nn & 7, dl = nn >> 3;
            f16x8 v = *(const f16x8*)&Ep[nn][mg * 8];
            *(f16x8*)&vT[((size_t)(h * DD + (n0b >> 3) + dl)) * BT +
                         m0b + mg * 8] = v;
        }
    }
}

// ---------------------------------------------------------------------------
// Output GEMM: out = ctx(f16) @ Wo (f16) -> fp32. Tile 64x64, BK=64.
// ---------------------------------------------------------------------------
__global__ __launch_bounds__(256) void outmm_k(const f16* __restrict__ Af,
                                               const f16* __restrict__ WThi,
                                               float* __restrict__ out) {
    __shared__ __align__(16) f16 Ah_s[2][64][72];
    __shared__ __align__(16) f16 Wh_s[2][64][72];

    const int t = threadIdx.x;
    const int w = t >> 6, l = t & 63;
    const int wm = w >> 1, wn = w & 1;
    const int fr = l & 15, fc = l >> 4;
    const int m0b = blockIdx.x * 64;
    const int n0b = blockIdx.y * 64;
    const int sr = t >> 2, sch = t & 3;

    f32x4 acc[2][2];
#pragma unroll
    for (int i = 0; i < 2; ++i)
#pragma unroll
        for (int j = 0; j < 2; ++j) acc[i][j] = f32x4{0.f, 0.f, 0.f, 0.f};

    f16x8 af[2], wf[2];
    auto loadAB = [&](int k0) {
#pragma unroll
        for (int i = 0; i < 2; ++i) {
            af[i] = *(const f16x8*)&Af[(size_t)(m0b + sr) * EE + k0 + sch * 16 + i * 8];
            wf[i] = *(const f16x8*)&WThi[(size_t)(n0b + sr) * EE + k0 + sch * 16 + i * 8];
        }
    };
    auto stage = [&](int bf) {
#pragma unroll
        for (int i = 0; i < 2; ++i) {
            *(f16x8*)&Ah_s[bf][sr][sch * 16 + i * 8] = af[i];
            *(f16x8*)&Wh_s[bf][sr][sch * 16 + i * 8] = wf[i];
        }
    };

    loadAB(0);
    stage(0);
    __syncthreads();
    int cur = 0;
    for (int ks = 0; ks < 8; ++ks) {
        if (ks < 7) loadAB((ks + 1) * 64);
        f16x8 Ahf[2][2], Bhf[2][2];
#pragma unroll
        for (int mi = 0; mi < 2; ++mi)
#pragma unroll
            for (int kb = 0; kb < 2; ++kb)
                Ahf[mi][kb] =
                    *(const f16x8*)&Ah_s[cur][wm * 32 + mi * 16 + fr][kb * 32 + fc * 8];
#pragma unroll
        for (int nj = 0; nj < 2; ++nj)
#pragma unroll
            for (int kb = 0; kb < 2; ++kb)
                Bhf[nj][kb] =
                    *(const f16x8*)&Wh_s[cur][wn * 32 + nj * 16 + fr][kb * 32 + fc * 8];
        __builtin_amdgcn_s_setprio(1);
#pragma unroll
        for (int mi = 0; mi < 2; ++mi)
#pragma unroll
            for (int nj = 0; nj < 2; ++nj)
#pragma unroll
                for (int kb = 0; kb < 2; ++kb)
                    acc[mi][nj] = __builtin_amdgcn_mfma_f32_16x16x32_f16(
                        Ahf[mi][kb], Bhf[nj][kb], acc[mi][nj], 0, 0, 0);
        __builtin_amdgcn_s_setprio(0);
        if (ks < 7) stage(cur ^ 1);
        __syncthreads();
        cur ^= 1;
    }

    float* o = out;
#pragma unroll
    for (int mi = 0; mi < 2; ++mi)
#pragma unroll
        for (int nj = 0; nj < 2; ++nj)
#pragma unroll
            for (int r = 0; r < 4; ++r)
                o[(size_t)(m0b + wm * 32 + mi * 16 + fc * 4 + r) * EE +
                  n0b + wn * 32 + nj * 16 + fr] = acc[mi][nj][r];
}

// ---------------------------------------------------------------------------
// MFMA flash attention: 64-key tiles, double-buffered LDS + reg-staged
// prefetch, defer-max (THR=8). Block = 4 waves x 16 q rows. Grid (16,8,4).
// ---------------------------------------------------------------------------
__global__ __launch_bounds__(256) void attn_mfma_k(const f16* __restrict__ qhiP,
    const f16* __restrict__ qloP, const f16* __restrict__ khiP,
    const f16* __restrict__ kloP, const f16* __restrict__ vTP,
    f16* __restrict__ ctx) {
    __shared__ __align__(16) f16 Khi[2][64][64];   // XOR-swizzled 16B chunks
    __shared__ __align__(16) f16 Klo[2][64][64];
    __shared__ __align__(16) f16 VT[2][64][72];    // [d][key], padded
    __shared__ __align__(16) f16 Pl[4][16][88];    // per-wave P[q][key]

    const int t  = threadIdx.x;
    const int w  = t >> 6;
    const int l  = t & 63;
    const int lg = l >> 4;
    const int lq = l & 15;
    const int q0 = blockIdx.x * 64 + w * 16;
    const int h  = blockIdx.y;
    const int b  = blockIdx.z;
    const size_t plane = ((size_t)h * BT + (size_t)b * TT) * DD;

    f16x8 Qhi[2], Qlo[2];
#pragma unroll
    for (int kf = 0; kf < 2; ++kf) {
        size_t qo = plane + (size_t)(q0 + lq) * DD + kf * 32 + lg * 8;
        Qhi[kf] = *(const f16x8*)&qhiP[qo];
        Qlo[kf] = *(const f16x8*)&qloP[qo];
    }

    f32x4 Oacc[4];
#pragma unroll
    for (int i = 0; i < 4; ++i) Oacc[i] = f32x4{0.f, 0.f, 0.f, 0.f};
    float m = -1e30f, lsum = 0.f;

    const int sr = t >> 2, sch = t & 3;
    f16x8 kh[2], kl[2], vv[2];

    auto loadKV = [&](int kt0) {
        size_t off = plane + (size_t)(kt0 + sr) * DD + sch * 16;
        kh[0] = *(const f16x8*)&khiP[off];
        kh[1] = *(const f16x8*)&khiP[off + 8];
        kl[0] = *(const f16x8*)&kloP[off];
        kl[1] = *(const f16x8*)&kloP[off + 8];
        size_t voff = ((size_t)h * DD + sr) * BT + (size_t)b * TT + kt0 + sch * 16;
        vv[0] = *(const f16x8*)&vTP[voff];
        vv[1] = *(const f16x8*)&vTP[voff + 8];
    };
    auto stageKV = [&](int bf) {
#pragma unroll
        for (int i = 0; i < 2; ++i) {
            int chunk = sch * 2 + i;
            int dsw = chunk ^ (sr & 7);
            *(f16x8*)&Khi[bf][sr][dsw * 8] = kh[i];
            *(f16x8*)&Klo[bf][sr][dsw * 8] = kl[i];
            *(f16x8*)&VT[bf][sr][chunk * 8] = vv[i];
        }
    };

    loadKV(0);
    stageKV(0);
    __syncthreads();
    int cur = 0;

    for (int kt0 = 0; kt0 < TT; kt0 += 64) {
        if (kt0 + 64 < TT) loadKV(kt0 + 64);

        // ---- QK^T (swapped): S^T[key][q], 3-product split fp16 ----
        f32x4 Sc[4];
        __builtin_amdgcn_s_setprio(1);
#pragma unroll
        for (int kt = 0; kt < 4; ++kt) {
            f32x4 c = f32x4{0.f, 0.f, 0.f, 0.f};
            int keyr = kt * 16 + lq;
#pragma unroll
            for (int kf = 0; kf < 2; ++kf) {
                int dblk = kf * 4 + lg;
                int sw = dblk ^ (keyr & 7);
                f16x8 ahi = *(const f16x8*)&Khi[cur][keyr][sw * 8];
                f16x8 alo = *(const f16x8*)&Klo[cur][keyr][sw * 8];
                c = __builtin_amdgcn_mfma_f32_16x16x32_f16(ahi, Qhi[kf], c, 0, 0, 0);
                c = __builtin_amdgcn_mfma_f32_16x16x32_f16(ahi, Qlo[kf], c, 0, 0, 0);
                c = __builtin_amdgcn_mfma_f32_16x16x32_f16(alo, Qhi[kf], c, 0, 0, 0);
            }
            Sc[kt] = c;
        }
        __builtin_amdgcn_s_setprio(0);

        // ---- online softmax for q-row lq (16 keys/lane) ----
        float s[16];
#pragma unroll
        for (int kt = 0; kt < 4; ++kt)
#pragma unroll
            for (int r = 0; r < 4; ++r) s[kt * 4 + r] = Sc[kt][r];
        float tm = s[0];
#pragma unroll
        for (int i = 1; i < 16; ++i) tm = fmaxf(tm, s[i]);
        tm = fmaxf(tm, __shfl_xor(tm, 16));
        tm = fmaxf(tm, __shfl_xor(tm, 32));

        bool skip = __all(tm <= m + 8.0f);
        float Mn = m, corr = 1.0f;
        if (!skip) {
            Mn = fmaxf(m, tm);
            corr = __expf(m - Mn);
        }
        float ps = 0.f;
        f16 ph[16];
#pragma unroll
        for (int i = 0; i < 16; ++i) {
            float p = __expf(s[i] - Mn);
            ps += p;
            ph[i] = (f16)p;
        }
        ps += __shfl_xor(ps, 16);
        ps += __shfl_xor(ps, 32);
        if (skip) {
            lsum += ps;
        } else {
            lsum = lsum * corr + ps;
            m = Mn;
        }

        // ---- write P (fp16 packed pairs) ----
#pragma unroll
        for (int kt = 0; kt < 4; ++kt)
#pragma unroll
            for (int rp = 0; rp < 4; rp += 2) {
                union { f16 h; unsigned short u; } u0, u1;
                u0.h = ph[kt * 4 + rp]; u1.h = ph[kt * 4 + rp + 1];
                unsigned int pk = ((unsigned int)u1.u << 16) | u0.u;
                *(unsigned int*)&Pl[w][lq][kt * 16 + lg * 4 + rp] = pk;
            }

        if (!skip) {
            float cq[4];
#pragma unroll
            for (int r = 0; r < 4; ++r) cq[r] = __shfl(corr, lg * 4 + r);
#pragma unroll
            for (int dvt = 0; dvt < 4; ++dvt)
#pragma unroll
                for (int r = 0; r < 4; ++r) Oacc[dvt][r] *= cq[r];
        }

        // ---- PV: O += P @ V ----
        __builtin_amdgcn_s_setprio(1);
#pragma unroll
        for (int kf = 0; kf < 2; ++kf) {
            f16x8 pa = *(const f16x8*)&Pl[w][lq][kf * 32 + lg * 8];
#pragma unroll
            for (int dvt = 0; dvt < 4; ++dvt) {
                f16x8 bv = *(const f16x8*)&VT[cur][dvt * 16 + lq][kf * 32 + lg * 8];
                Oacc[dvt] = __builtin_amdgcn_mfma_f32_16x16x32_f16(pa, bv, Oacc[dvt], 0, 0, 0);
            }
        }
        __builtin_amdgcn_s_setprio(0);

        if (kt0 + 64 < TT) stageKV(cur ^ 1);
        __syncthreads();
        cur ^= 1;
    }

    float linv = 1.0f / lsum;
    float lq4[4];
#pragma unroll
    for (int r = 0; r < 4; ++r) lq4[r] = __shfl(linv, lg * 4 + r);
#pragma unroll
    for (int r = 0; r < 4; ++r) {
        f16* crow = ctx + (size_t)(b * TT + q0 + lg * 4 + r) * EE + h * DD;
#pragma unroll
        for (int dvt = 0; dvt < 4; ++dvt)
            crow[dvt * 16 + lq] = (f16)(Oacc[dvt][r] * lq4[r]);
    }
}

// ---------------------------------------------------------------------------
extern "C" void kernel_launch(void* const* d_in, const int* in_sizes, int n_in,
                              void* d_out, int out_size, void* d_ws, size_t ws_size,
                              hipStream_t stream) {
    const float* q  = (const float*)d_in[0];
    const float* kv = (const float*)d_in[1];
    const float* Wq = (const float*)d_in[2];
    const float* Wk = (const float*)d_in[3];
    const float* Wv = (const float*)d_in[4];
    const float* Wo = (const float*)d_in[5];
    float* out = (float*)d_out;

    f16* ws = (f16*)d_ws;
    const size_t PL  = (size_t)HH * BT * DD;   // 2,097,152 f16 per plane
    const size_t WPL = (size_t)EE * EE;
    f16* qhi = ws + 0 * PL;
    f16* qlo = ws + 1 * PL;
    f16* khi = ws + 2 * PL;
    f16* klo = ws + 3 * PL;
    f16* vT  = ws + 4 * PL;      // [H][64][BT]
    f16* ctx = ws + 5 * PL;      // [BT][512]
    f16* wqh = ws + 6 * PL;
    f16* wql = wqh + 1 * WPL;
    f16* wkh = wqh + 2 * WPL;
    f16* wkl = wqh + 3 * WPL;
    f16* wvh = wqh + 4 * WPL;
    f16* woh = wqh + 5 * WPL;

    prep_w_k<<<dim3((EE * EE) / 256, 4), dim3(256), 0, stream>>>(
        Wq, Wk, Wv, Wo, wqh, wql, wkh, wkl, wvh, woh);

    proj_k<<<dim3(BT / 128, EE / 64, 2), dim3(256), 0, stream>>>(
        q, kv, wqh, wql, wkh, wkl, wvh, qhi, qlo, khi, klo, vT);

    attn_mfma_k<<<dim3(TT / 64, HH, BB), dim3(256), 0, stream>>>(
        qhi, qlo, khi, klo, vT, ctx);

    outmm_k<<<dim3(BT / 64, EE / 64), dim3(256), 0, stream>>>(ctx, woh, out);
}